// Round 1
// baseline (424.113 us; speedup 1.0000x reference)
//
#include <hip/hip_runtime.h>

using u16 = unsigned short;
using u32 = unsigned int;

constexpr int Bb = 4, T = 2048, C = 1024, F = 4096;

typedef __attribute__((ext_vector_type(8))) short short8v;
typedef __attribute__((ext_vector_type(4))) float f32x4;

__device__ __forceinline__ u16 f2bf(float f) {
  u32 bits = __builtin_bit_cast(u32, f);
  u32 r = bits + 0x7FFFu + ((bits >> 16) & 1u);
  return (u16)(r >> 16);
}
__device__ __forceinline__ float bf2f(u16 u) {
  u32 b = ((u32)u) << 16;
  return __builtin_bit_cast(float, b);
}

__device__ __forceinline__ void gld16(const u16* g, u16* l) {
  __builtin_amdgcn_global_load_lds(
      (const __attribute__((address_space(1))) u32*)g,
      (__attribute__((address_space(3))) u32*)l, 16, 0, 0);
}

// ---------------- LN1 + RoPE ----------------
__global__ __launch_bounds__(256) void ln1_rope_k(
    const float* __restrict__ x, const float* __restrict__ gw,
    const float* __restrict__ bw, u16* __restrict__ qk, u16* __restrict__ vv) {
  const int row = blockIdx.x;            // b*T + t
  const int t = row & (T - 1);
  const int tid = threadIdx.x;
  const float4 xv = ((const float4*)(x + (size_t)row * C))[tid];
  float s = xv.x + xv.y + xv.z + xv.w;
  float s2 = xv.x * xv.x + xv.y * xv.y + xv.z * xv.z + xv.w * xv.w;
#pragma unroll
  for (int o = 32; o; o >>= 1) { s += __shfl_xor(s, o, 64); s2 += __shfl_xor(s2, o, 64); }
  __shared__ float red[8];
  if ((tid & 63) == 0) { red[(tid >> 6) * 2] = s; red[(tid >> 6) * 2 + 1] = s2; }
  __syncthreads();
  s = red[0] + red[2] + red[4] + red[6];
  s2 = red[1] + red[3] + red[5] + red[7];
  const float mu = s * (1.f / C);
  const float var = s2 * (1.f / C) - mu * mu;
  const float rstd = rsqrtf(var + 1e-5f);
  const float4 gv = ((const float4*)gw)[tid];
  const float4 bv = ((const float4*)bw)[tid];
  float nn[4];
  nn[0] = (xv.x - mu) * rstd * gv.x + bv.x;
  nn[1] = (xv.y - mu) * rstd * gv.y + bv.y;
  nn[2] = (xv.z - mu) * rstd * gv.z + bv.z;
  nn[3] = (xv.w - mu) * rstd * gv.w + bv.w;
  __shared__ float ns[C];
  const int c0 = tid * 4;
  ns[c0] = nn[0]; ns[c0 + 1] = nn[1]; ns[c0 + 2] = nn[2]; ns[c0 + 3] = nn[3];
  uint2 pv;
  pv.x = (u32)f2bf(nn[0]) | ((u32)f2bf(nn[1]) << 16);
  pv.y = (u32)f2bf(nn[2]) | ((u32)f2bf(nn[3]) << 16);
  ((uint2*)(vv + (size_t)row * C))[tid] = pv;
  __syncthreads();
  float o[4];
#pragma unroll
  for (int e = 0; e < 4; e++) {
    const int c = c0 + e;
    const int j = c & (C / 2 - 1);
    const float invf = exp2f((float)j * (-13.287712379549449f / 512.f));
    float sn, cn;
    sincosf((float)t * invf, &sn, &cn);
    const float other = (c < C / 2) ? ns[c + C / 2] : ns[c - C / 2];
    o[e] = (c < C / 2) ? nn[e] * cn - other * sn : nn[e] * cn + other * sn;
  }
  uint2 qv;
  qv.x = (u32)f2bf(o[0]) | ((u32)f2bf(o[1]) << 16);
  qv.y = (u32)f2bf(o[2]) | ((u32)f2bf(o[3]) << 16);
  ((uint2*)(qk + (size_t)row * C))[tid] = qv;
}

// ---------------- LN2 ----------------
__global__ __launch_bounds__(256) void ln2_k(
    const float* __restrict__ xin, const float* __restrict__ gw,
    const float* __restrict__ bw, u16* __restrict__ out) {
  const int row = blockIdx.x;
  const int tid = threadIdx.x;
  const float4 xv = ((const float4*)(xin + (size_t)row * C))[tid];
  float s = xv.x + xv.y + xv.z + xv.w;
  float s2 = xv.x * xv.x + xv.y * xv.y + xv.z * xv.z + xv.w * xv.w;
#pragma unroll
  for (int o = 32; o; o >>= 1) { s += __shfl_xor(s, o, 64); s2 += __shfl_xor(s2, o, 64); }
  __shared__ float red[8];
  if ((tid & 63) == 0) { red[(tid >> 6) * 2] = s; red[(tid >> 6) * 2 + 1] = s2; }
  __syncthreads();
  s = red[0] + red[2] + red[4] + red[6];
  s2 = red[1] + red[3] + red[5] + red[7];
  const float mu = s * (1.f / C);
  const float var = s2 * (1.f / C) - mu * mu;
  const float rstd = rsqrtf(var + 1e-5f);
  const float4 gv = ((const float4*)gw)[tid];
  const float4 bv = ((const float4*)bw)[tid];
  uint2 pv;
  pv.x = (u32)f2bf((xv.x - mu) * rstd * gv.x + bv.x) |
         ((u32)f2bf((xv.y - mu) * rstd * gv.y + bv.y) << 16);
  pv.y = (u32)f2bf((xv.z - mu) * rstd * gv.z + bv.z) |
         ((u32)f2bf((xv.w - mu) * rstd * gv.w + bv.w) << 16);
  ((uint2*)(out + (size_t)row * C))[tid] = pv;
}

// ---------------- softmax (fp32 in, bf16 out in-place, ld becomes 2T) ----------------
__global__ __launch_bounds__(256) void softmax_rows(float* __restrict__ S) {
  float* row = S + (size_t)blockIdx.x * T;
  const int tid = threadIdx.x;
  const float4 a = ((const float4*)row)[2 * tid];
  const float4 b = ((const float4*)row)[2 * tid + 1];
  float v[8] = {a.x, a.y, a.z, a.w, b.x, b.y, b.z, b.w};
  float m = v[0];
#pragma unroll
  for (int i = 1; i < 8; i++) m = fmaxf(m, v[i]);
#pragma unroll
  for (int o = 32; o; o >>= 1) m = fmaxf(m, __shfl_xor(m, o, 64));
  __shared__ float red[4];
  if ((tid & 63) == 0) red[tid >> 6] = m;
  __syncthreads();
  m = fmaxf(fmaxf(red[0], red[1]), fmaxf(red[2], red[3]));
  float s = 0.f;
#pragma unroll
  for (int i = 0; i < 8; i++) { v[i] = __expf(v[i] - m); s += v[i]; }
#pragma unroll
  for (int o = 32; o; o >>= 1) s += __shfl_xor(s, o, 64);
  __shared__ float red2[4];
  __syncthreads();
  if ((tid & 63) == 0) red2[tid >> 6] = s;
  __syncthreads();
  s = red2[0] + red2[1] + red2[2] + red2[3];
  const float inv = 1.f / s;
  uint4 w;
  w.x = (u32)f2bf(v[0] * inv) | ((u32)f2bf(v[1] * inv) << 16);
  w.y = (u32)f2bf(v[2] * inv) | ((u32)f2bf(v[3] * inv) << 16);
  w.z = (u32)f2bf(v[4] * inv) | ((u32)f2bf(v[5] * inv) << 16);
  w.w = (u32)f2bf(v[6] * inv) | ((u32)f2bf(v[7] * inv) << 16);
  ((uint4*)row)[tid] = w;
}

// ---------------- transposes ----------------
__global__ __launch_bounds__(256) void transp_bf16(
    const u16* __restrict__ in, u16* __restrict__ out, int R, int Cd) {
  __shared__ u16 tle[32][33];
  const size_t z = (size_t)blockIdx.z * R * Cd;
  const int c0 = blockIdx.x * 32, r0 = blockIdx.y * 32;
  const int tx = threadIdx.x, ty = threadIdx.y;
#pragma unroll
  for (int j = 0; j < 32; j += 8)
    tle[ty + j][tx] = in[z + (size_t)(r0 + ty + j) * Cd + c0 + tx];
  __syncthreads();
#pragma unroll
  for (int j = 0; j < 32; j += 8)
    out[z + (size_t)(c0 + ty + j) * R + r0 + tx] = tle[tx][ty + j];
}

__global__ __launch_bounds__(256) void transp_f32_bf16(
    const float* __restrict__ in, u16* __restrict__ out, int R, int Cd) {
  __shared__ float tle[32][33];
  const int c0 = blockIdx.x * 32, r0 = blockIdx.y * 32;
  const int tx = threadIdx.x, ty = threadIdx.y;
#pragma unroll
  for (int j = 0; j < 32; j += 8)
    tle[ty + j][tx] = in[(size_t)(r0 + ty + j) * Cd + c0 + tx];
  __syncthreads();
#pragma unroll
  for (int j = 0; j < 32; j += 8)
    out[(size_t)(c0 + ty + j) * R + r0 + tx] = f2bf(tle[tx][ty + j]);
}

// ---------------- BT-layout MFMA GEMM: out[i][j] = sum_k A[i][k]*B[j][k] ----------------
// EPI 0: outF = acc*scale      (attention logits, fp32)
// EPI 1: outF = resid + acc    (PV + residual)
// EPI 2: outB = bf16(gelu(acc + bias[col]))
// EPI 3: outF += acc + bias[col]
template <int EPI>
__global__ __launch_bounds__(256) void gemm_bt(
    const u16* __restrict__ A, const u16* __restrict__ Bm, int lda, int ldb,
    int K, long long strideA, long long strideB, float* __restrict__ outF,
    u16* __restrict__ outB, int ldo, long long strideO,
    const float* __restrict__ bias, const float* __restrict__ resid,
    float scale) {
  __shared__ alignas(16) u16 As[128 * 32];
  __shared__ alignas(16) u16 Bs[128 * 32];
  const int bz = blockIdx.z;
  A += (size_t)bz * strideA;
  Bm += (size_t)bz * strideB;
  const size_t obase = (size_t)bz * strideO;
  const int tileM = blockIdx.y * 128, tileN = blockIdx.x * 128;
  const int tid = threadIdx.x;
  const int lane = tid & 63, wid = tid >> 6;
  const int wr = wid >> 1, wc = wid & 1;
  const int lr = lane & 15, lg = lane >> 4;

  f32x4 acc[4][4];
#pragma unroll
  for (int i = 0; i < 4; i++)
#pragma unroll
    for (int j = 0; j < 4; j++) acc[i][j] = (f32x4){0.f, 0.f, 0.f, 0.f};

  const int srow = tid >> 2;
  const int scol = (tid & 3) << 3;
  const u16* gA0 = A + (size_t)(tileM + srow) * lda + scol;
  const u16* gA1 = A + (size_t)(tileM + 64 + srow) * lda + scol;
  const u16* gB0 = Bm + (size_t)(tileN + srow) * ldb + scol;
  const u16* gB1 = Bm + (size_t)(tileN + 64 + srow) * ldb + scol;
  u16* lA = &As[tid * 8];
  u16* lB = &Bs[tid * 8];

  for (int k0 = 0; k0 < K; k0 += 32) {
    gld16(gA0 + k0, lA);
    gld16(gA1 + k0, lA + 2048);
    gld16(gB0 + k0, lB);
    gld16(gB1 + k0, lB + 2048);
    __syncthreads();
    short8v af[4], bf[4];
#pragma unroll
    for (int i = 0; i < 4; i++)
      af[i] = *(const short8v*)&As[(wr * 64 + i * 16 + lr) * 32 + lg * 8];
#pragma unroll
    for (int j = 0; j < 4; j++)
      bf[j] = *(const short8v*)&Bs[(wc * 64 + j * 16 + lr) * 32 + lg * 8];
#pragma unroll
    for (int i = 0; i < 4; i++)
#pragma unroll
      for (int j = 0; j < 4; j++)
        acc[i][j] =
            __builtin_amdgcn_mfma_f32_16x16x32_bf16(af[i], bf[j], acc[i][j], 0, 0, 0);
    __syncthreads();
  }

#pragma unroll
  for (int i = 0; i < 4; i++) {
    const int r0 = tileM + wr * 64 + i * 16 + lg * 4;
#pragma unroll
    for (int j = 0; j < 4; j++) {
      const int cc = tileN + wc * 64 + j * 16 + lr;
#pragma unroll
      for (int r = 0; r < 4; r++) {
        const size_t o = obase + (size_t)(r0 + r) * ldo + cc;
        const float av = acc[i][j][r];
        if constexpr (EPI == 0) {
          outF[o] = av * scale;
        } else if constexpr (EPI == 1) {
          outF[o] = resid[o] + av;
        } else if constexpr (EPI == 2) {
          const float zz = av + bias[cc];
          const float gl = 0.5f * zz * (1.0f + erff(zz * 0.70710678118654752f));
          outB[o] = f2bf(gl);
        } else {
          outF[o] = outF[o] + av + bias[cc];
        }
      }
    }
  }
}

extern "C" void kernel_launch(void* const* d_in, const int* in_sizes, int n_in,
                              void* d_out, int out_size, void* d_ws,
                              size_t ws_size, hipStream_t stream) {
  const float* x = (const float*)d_in[0];
  const float* ln1_g = (const float*)d_in[1];
  const float* ln1_b = (const float*)d_in[2];
  const float* ln2_g = (const float*)d_in[3];
  const float* ln2_b = (const float*)d_in[4];
  const float* W1 = (const float*)d_in[5];
  const float* b1 = (const float*)d_in[6];
  const float* W2 = (const float*)d_in[7];
  const float* b2 = (const float*)d_in[8];
  float* out = (float*)d_out;
  char* ws = (char*)d_ws;

  u16* qk = (u16*)(ws + 0);                         // 16 MB  [B,T,C] bf16 (q == k)
  u16* vv = (u16*)(ws + (16LL << 20));              // 16 MB  [B,T,C] bf16
  u16* vT = (u16*)(ws + (32LL << 20));              // 16 MB  [B,C,T] bf16
  float* S = (float*)(ws + (48LL << 20));           // 64 MB  [B,T,T] fp32 -> bf16 P in-place
  u16* ln2h = (u16*)(ws + 0);                       // reuse qk region
  u16* W1T = (u16*)(ws + (16LL << 20));             // 8 MB   [F,C]
  u16* W2T = (u16*)(ws + (24LL << 20));             // 8 MB   [C,F]
  u16* h1 = (u16*)(ws + (48LL << 20));              // 64 MB  [B*T,F] bf16 (reuse S)

  ln1_rope_k<<<Bb * T, 256, 0, stream>>>(x, ln1_g, ln1_b, qk, vv);
  transp_bf16<<<dim3(C / 32, T / 32, Bb), dim3(32, 8), 0, stream>>>(vv, vT, T, C);

  // S = scale * q . q^T   (M=N=T, K=C, batched)
  gemm_bt<0><<<dim3(T / 128, T / 128, Bb), 256, 0, stream>>>(
      qk, qk, C, C, C, (long long)T * C, (long long)T * C, S, nullptr, T,
      (long long)T * T, nullptr, nullptr, 1.f / 32.f);

  softmax_rows<<<Bb * T, 256, 0, stream>>>(S);

  // out = x + P . V   (A = P bf16 with ld 2T, B = vT, M=T, N=C, K=T)
  gemm_bt<1><<<dim3(C / 128, T / 128, Bb), 256, 0, stream>>>(
      (const u16*)S, vT, 2 * T, T, T, 2LL * T * T, (long long)C * T, out,
      nullptr, C, (long long)T * C, nullptr, x, 1.f);

  ln2_k<<<Bb * T, 256, 0, stream>>>(out, ln2_g, ln2_b, ln2h);
  transp_f32_bf16<<<dim3(F / 32, C / 32, 1), dim3(32, 8), 0, stream>>>(W1, W1T, C, F);
  transp_f32_bf16<<<dim3(C / 32, F / 32, 1), dim3(32, 8), 0, stream>>>(W2, W2T, F, C);

  // h1 = gelu(ln2h . W1 + b1)   (M=B*T, N=F, K=C)
  gemm_bt<2><<<dim3(F / 128, (Bb * T) / 128, 1), 256, 0, stream>>>(
      ln2h, W1T, C, C, C, 0, 0, nullptr, h1, F, 0, b1, nullptr, 1.f);

  // out += h1 . W2 + b2   (M=B*T, N=C, K=F)
  gemm_bt<3><<<dim3(C / 128, (Bb * T) / 128, 1), 256, 0, stream>>>(
      h1, W2T, F, F, F, 0, 0, out, nullptr, C, 0, b2, nullptr, 1.f);
}

// Round 2
// 344.869 us; speedup vs baseline: 1.2298x; 1.2298x over previous
//
#include <hip/hip_runtime.h>

using u16 = unsigned short;
using u32 = unsigned int;

constexpr int Bb = 4, T = 2048, C = 1024, F = 4096;

typedef __attribute__((ext_vector_type(8))) short short8v;
typedef __attribute__((ext_vector_type(4))) float f32x4;

__device__ __forceinline__ u16 f2bf(float f) {
  u32 bits = __builtin_bit_cast(u32, f);
  u32 r = bits + 0x7FFFu + ((bits >> 16) & 1u);
  return (u16)(r >> 16);
}

__device__ __forceinline__ void gld16(const u16* g, u16* l) {
  __builtin_amdgcn_global_load_lds(
      (const __attribute__((address_space(1))) u32*)g,
      (__attribute__((address_space(3))) u32*)l, 16, 0, 0);
}

// ---------------- LN1 + RoPE ----------------
__global__ __launch_bounds__(256) void ln1_rope_k(
    const float* __restrict__ x, const float* __restrict__ gw,
    const float* __restrict__ bw, u16* __restrict__ qk, u16* __restrict__ vv) {
  const int row = blockIdx.x;            // b*T + t
  const int t = row & (T - 1);
  const int tid = threadIdx.x;
  const float4 xv = ((const float4*)(x + (size_t)row * C))[tid];
  float s = xv.x + xv.y + xv.z + xv.w;
  float s2 = xv.x * xv.x + xv.y * xv.y + xv.z * xv.z + xv.w * xv.w;
#pragma unroll
  for (int o = 32; o; o >>= 1) { s += __shfl_xor(s, o, 64); s2 += __shfl_xor(s2, o, 64); }
  __shared__ float red[8];
  if ((tid & 63) == 0) { red[(tid >> 6) * 2] = s; red[(tid >> 6) * 2 + 1] = s2; }
  __syncthreads();
  s = red[0] + red[2] + red[4] + red[6];
  s2 = red[1] + red[3] + red[5] + red[7];
  const float mu = s * (1.f / C);
  const float var = s2 * (1.f / C) - mu * mu;
  const float rstd = rsqrtf(var + 1e-5f);
  const float4 gv = ((const float4*)gw)[tid];
  const float4 bv = ((const float4*)bw)[tid];
  float nn[4];
  nn[0] = (xv.x - mu) * rstd * gv.x + bv.x;
  nn[1] = (xv.y - mu) * rstd * gv.y + bv.y;
  nn[2] = (xv.z - mu) * rstd * gv.z + bv.z;
  nn[3] = (xv.w - mu) * rstd * gv.w + bv.w;
  __shared__ float ns[C];
  const int c0 = tid * 4;
  ns[c0] = nn[0]; ns[c0 + 1] = nn[1]; ns[c0 + 2] = nn[2]; ns[c0 + 3] = nn[3];
  uint2 pv;
  pv.x = (u32)f2bf(nn[0]) | ((u32)f2bf(nn[1]) << 16);
  pv.y = (u32)f2bf(nn[2]) | ((u32)f2bf(nn[3]) << 16);
  ((uint2*)(vv + (size_t)row * C))[tid] = pv;
  __syncthreads();
  float o[4];
#pragma unroll
  for (int e = 0; e < 4; e++) {
    const int c = c0 + e;
    const int j = c & (C / 2 - 1);
    const float invf = exp2f((float)j * (-13.287712379549449f / 512.f));
    float sn, cn;
    sincosf((float)t * invf, &sn, &cn);
    const float other = (c < C / 2) ? ns[c + C / 2] : ns[c - C / 2];
    o[e] = (c < C / 2) ? nn[e] * cn - other * sn : nn[e] * cn + other * sn;
  }
  uint2 qv;
  qv.x = (u32)f2bf(o[0]) | ((u32)f2bf(o[1]) << 16);
  qv.y = (u32)f2bf(o[2]) | ((u32)f2bf(o[3]) << 16);
  ((uint2*)(qk + (size_t)row * C))[tid] = qv;
}

// ---------------- LN2 ----------------
__global__ __launch_bounds__(256) void ln2_k(
    const float* __restrict__ xin, const float* __restrict__ gw,
    const float* __restrict__ bw, u16* __restrict__ out) {
  const int row = blockIdx.x;
  const int tid = threadIdx.x;
  const float4 xv = ((const float4*)(xin + (size_t)row * C))[tid];
  float s = xv.x + xv.y + xv.z + xv.w;
  float s2 = xv.x * xv.x + xv.y * xv.y + xv.z * xv.z + xv.w * xv.w;
#pragma unroll
  for (int o = 32; o; o >>= 1) { s += __shfl_xor(s, o, 64); s2 += __shfl_xor(s2, o, 64); }
  __shared__ float red[8];
  if ((tid & 63) == 0) { red[(tid >> 6) * 2] = s; red[(tid >> 6) * 2 + 1] = s2; }
  __syncthreads();
  s = red[0] + red[2] + red[4] + red[6];
  s2 = red[1] + red[3] + red[5] + red[7];
  const float mu = s * (1.f / C);
  const float var = s2 * (1.f / C) - mu * mu;
  const float rstd = rsqrtf(var + 1e-5f);
  const float4 gv = ((const float4*)gw)[tid];
  const float4 bv = ((const float4*)bw)[tid];
  uint2 pv;
  pv.x = (u32)f2bf((xv.x - mu) * rstd * gv.x + bv.x) |
         ((u32)f2bf((xv.y - mu) * rstd * gv.y + bv.y) << 16);
  pv.y = (u32)f2bf((xv.z - mu) * rstd * gv.z + bv.z) |
         ((u32)f2bf((xv.w - mu) * rstd * gv.w + bv.w) << 16);
  ((uint2*)(out + (size_t)row * C))[tid] = pv;
}

// ---------------- softmax (fp32 in, bf16 out in-place, ld becomes 2T) ----------------
__global__ __launch_bounds__(256) void softmax_rows(float* __restrict__ S) {
  float* row = S + (size_t)blockIdx.x * T;
  const int tid = threadIdx.x;
  const float4 a = ((const float4*)row)[2 * tid];
  const float4 b = ((const float4*)row)[2 * tid + 1];
  float v[8] = {a.x, a.y, a.z, a.w, b.x, b.y, b.z, b.w};
  float m = v[0];
#pragma unroll
  for (int i = 1; i < 8; i++) m = fmaxf(m, v[i]);
#pragma unroll
  for (int o = 32; o; o >>= 1) m = fmaxf(m, __shfl_xor(m, o, 64));
  __shared__ float red[4];
  if ((tid & 63) == 0) red[tid >> 6] = m;
  __syncthreads();
  m = fmaxf(fmaxf(red[0], red[1]), fmaxf(red[2], red[3]));
  float s = 0.f;
#pragma unroll
  for (int i = 0; i < 8; i++) { v[i] = __expf(v[i] - m); s += v[i]; }
#pragma unroll
  for (int o = 32; o; o >>= 1) s += __shfl_xor(s, o, 64);
  __shared__ float red2[4];
  __syncthreads();
  if ((tid & 63) == 0) red2[tid >> 6] = s;
  __syncthreads();
  s = red2[0] + red2[1] + red2[2] + red2[3];
  const float inv = 1.f / s;
  uint4 w;
  w.x = (u32)f2bf(v[0] * inv) | ((u32)f2bf(v[1] * inv) << 16);
  w.y = (u32)f2bf(v[2] * inv) | ((u32)f2bf(v[3] * inv) << 16);
  w.z = (u32)f2bf(v[4] * inv) | ((u32)f2bf(v[5] * inv) << 16);
  w.w = (u32)f2bf(v[6] * inv) | ((u32)f2bf(v[7] * inv) << 16);
  ((uint4*)row)[tid] = w;
}

// ---------------- transposes ----------------
__global__ __launch_bounds__(256) void transp_bf16(
    const u16* __restrict__ in, u16* __restrict__ out, int R, int Cd) {
  __shared__ u16 tle[32][33];
  const size_t z = (size_t)blockIdx.z * R * Cd;
  const int c0 = blockIdx.x * 32, r0 = blockIdx.y * 32;
  const int tx = threadIdx.x, ty = threadIdx.y;
#pragma unroll
  for (int j = 0; j < 32; j += 8)
    tle[ty + j][tx] = in[z + (size_t)(r0 + ty + j) * Cd + c0 + tx];
  __syncthreads();
#pragma unroll
  for (int j = 0; j < 32; j += 8)
    out[z + (size_t)(c0 + ty + j) * R + r0 + tx] = tle[tx][ty + j];
}

__global__ __launch_bounds__(256) void transp_f32_bf16(
    const float* __restrict__ in, u16* __restrict__ out, int R, int Cd) {
  __shared__ float tle[32][33];
  const int c0 = blockIdx.x * 32, r0 = blockIdx.y * 32;
  const int tx = threadIdx.x, ty = threadIdx.y;
#pragma unroll
  for (int j = 0; j < 32; j += 8)
    tle[ty + j][tx] = in[(size_t)(r0 + ty + j) * Cd + c0 + tx];
  __syncthreads();
#pragma unroll
  for (int j = 0; j < 32; j += 8)
    out[(size_t)(c0 + ty + j) * R + r0 + tx] = f2bf(tle[tx][ty + j]);
}

// ================= 8-phase 512-thread MFMA GEMM (BT layout) =================
// out[i][j] = sum_k A[i][k] * B[j][k]
// EPI 0: outF = acc*scale ; EPI 1: outF = resid + acc ;
// EPI 2: outB = bf16(gelu(acc+bias)) ; EPI 3: outF += acc + bias
template <int g, int MR, int NR, int NG>
__device__ __forceinline__ void mfma_group(short8v (&a)[MR][2], short8v (&b)[NR][2],
                                           f32x4 (&acc)[MR][NR]) {
#pragma unroll
  for (int n0 = 0; n0 < NG; ++n0)
#pragma unroll
    for (int m = 0; m < MR; ++m)
#pragma unroll
      for (int kk = 0; kk < 2; ++kk)
        acc[m][g * NG + n0] = __builtin_amdgcn_mfma_f32_16x16x32_bf16(
            a[m][kk], b[g * NG + n0][kk], acc[m][g * NG + n0], 0, 0, 0);
}

template <int BM, int BN, int WM, int WN, int EPI>
__global__ __launch_bounds__(512, 2) void gemm8p(
    const u16* __restrict__ A, const u16* __restrict__ Bm, int lda, int ldb,
    int K, long long strideA, long long strideB, float* __restrict__ outF,
    u16* __restrict__ outB, int ldo, long long strideO,
    const float* __restrict__ bias, const float* __restrict__ resid,
    float scale) {
  constexpr int MR = BM / WM / 16;   // M fragments per wave
  constexpr int NR = BN / WN / 16;   // N fragments per wave
  constexpr int NG = NR / 4;         // N frags per phase-group
  constexpr int LA = BM / 128;       // gld16 per A half-tile per thread
  constexpr int LB = BN / 128;
  constexpr int ABYTES = BM * 128;   // one A buffer (BK=64 bf16 = 128B/row)
  constexpr int BBYTES = BN * 128;
  constexpr int VS = 2 * LA + LB;    // steady-state vmcnt
  static_assert(NR % 4 == 0 && MR * 2 <= 16, "");

  __shared__ alignas(16) char ldsmem[2 * ABYTES + 2 * BBYTES];
  char* const ldsA = ldsmem;
  char* const ldsB = ldsmem + 2 * ABYTES;

  const int bz = blockIdx.z;
  A += (size_t)bz * strideA;
  Bm += (size_t)bz * strideB;
  const size_t obase = (size_t)bz * strideO;
  const int tileM = blockIdx.y * BM, tileN = blockIdx.x * BN;
  const int tid = threadIdx.x;
  const int lane = tid & 63, wid = tid >> 6;
  const int wr = wid / WN, wc = wid % WN;
  const int lr = lane & 15, lg = lane >> 4;
  const int aswz = (lr & 7) << 4;    // read-side XOR swizzle (row&7)<<4

  // staging: thread covers 16B at (row = tr, bytecol = (tid&7)*16), source
  // column pre-swizzled so linear LDS dest + swizzled read are consistent.
  const int tr = tid >> 3;
  const int colsw = ((((tid & 7) << 4) ^ ((tr & 7) << 4))) >> 1;  // element col
  const u16* Ab = A + (size_t)(tileM + tr) * lda + colsw;
  const u16* Bbp = Bm + (size_t)(tileN + tr) * ldb + colsw;
  const int NT = K >> 6;  // K-tiles of 64

  auto stageA = [&](int buf, int half, int k0) {
#pragma unroll
    for (int l = 0; l < LA; ++l)
      gld16(Ab + (size_t)(half * (BM / 2) + l * 64) * lda + k0,
            (u16*)&ldsA[buf * ABYTES + (half * (BM / 2) + l * 64) * 128 + tid * 16]);
  };
  auto stageB = [&](int buf, int half, int k0) {
#pragma unroll
    for (int l = 0; l < LB; ++l)
      gld16(Bbp + (size_t)(half * (BN / 2) + l * 64) * ldb + k0,
            (u16*)&ldsB[buf * BBYTES + (half * (BN / 2) + l * 64) * 128 + tid * 16]);
  };

  f32x4 acc[MR][NR];
#pragma unroll
  for (int m = 0; m < MR; ++m)
#pragma unroll
    for (int n = 0; n < NR; ++n) acc[m][n] = (f32x4){0.f, 0.f, 0.f, 0.f};
  short8v a[MR][2], b[NR][2];

  auto readA = [&](int buf) {
#pragma unroll
    for (int m = 0; m < MR; ++m)
#pragma unroll
      for (int kk = 0; kk < 2; ++kk)
        a[m][kk] = *(const short8v*)&ldsA[buf * ABYTES +
            (wr * (BM / WM) + m * 16 + lr) * 128 + ((kk * 64 + lg * 16) ^ aswz)];
  };
  auto readB0 = [&](int buf) {
#pragma unroll
    for (int n = 0; n < NG; ++n)
#pragma unroll
      for (int kk = 0; kk < 2; ++kk)
        b[n][kk] = *(const short8v*)&ldsB[buf * BBYTES +
            (wc * (BN / WN) + n * 16 + lr) * 128 + ((kk * 64 + lg * 16) ^ aswz)];
  };
  auto readB1 = [&](int buf) {
#pragma unroll
    for (int n = NG; n < NR; ++n)
#pragma unroll
      for (int kk = 0; kk < 2; ++kk)
        b[n][kk] = *(const short8v*)&ldsB[buf * BBYTES +
            (wc * (BN / WN) + n * 16 + lr) * 128 + ((kk * 64 + lg * 16) ^ aswz)];
  };

  // prologue: tile0 fully, tile1 {A0,A1,B0}; leaves VS loads in flight
  stageA(0, 0, 0); stageA(0, 1, 0); stageB(0, 0, 0); stageB(0, 1, 0);
  stageA(1, 0, 64); stageA(1, 1, 64); stageB(1, 0, 64);
  if constexpr (VS == 6) asm volatile("s_waitcnt vmcnt(6)" ::: "memory");
  else asm volatile("s_waitcnt vmcnt(4)" ::: "memory");
  __builtin_amdgcn_s_barrier();

  int cur = 0;
  for (int k = 0; k < NT; ++k) {
    const int nb = cur ^ 1;
    const int k1 = (k + 1) << 6, k2 = (k + 2) << 6;
    // ---- phase 0: read A(all)+B(group0); stage B1(k+1) -> other buffer
    readA(cur);
    readB0(cur);
    if (k + 1 < NT) stageB(nb, 1, k1);
    __builtin_amdgcn_s_barrier();
    __builtin_amdgcn_s_setprio(1);
    mfma_group<0, MR, NR, NG>(a, b, acc);
    __builtin_amdgcn_s_setprio(0);
    __builtin_amdgcn_s_barrier();
    // ---- phase 1: read B(rest); stage A0(k+2) -> cur (A region dead)
    readB1(cur);
    if (k + 2 < NT) stageA(cur, 0, k2);
    asm volatile("s_waitcnt lgkmcnt(0)" ::: "memory");  // harden: all B reads done
    __builtin_amdgcn_s_barrier();
    __builtin_amdgcn_s_setprio(1);
    mfma_group<1, MR, NR, NG>(a, b, acc);
    __builtin_amdgcn_s_setprio(0);
    __builtin_amdgcn_s_barrier();
    // ---- phase 2: stage A1(k+2)
    if (k + 2 < NT) stageA(cur, 1, k2);
    __builtin_amdgcn_s_barrier();
    __builtin_amdgcn_s_setprio(1);
    mfma_group<2, MR, NR, NG>(a, b, acc);
    __builtin_amdgcn_s_setprio(0);
    __builtin_amdgcn_s_barrier();
    // ---- phase 3: stage B0(k+2); counted vmcnt -> tile k+1 buffer complete
    if (k + 2 < NT) stageB(cur, 0, k2);
    if (k < NT - 2) {
      if constexpr (VS == 6) asm volatile("s_waitcnt vmcnt(6)" ::: "memory");
      else asm volatile("s_waitcnt vmcnt(4)" ::: "memory");
    } else if (k == NT - 2) {
      asm volatile("s_waitcnt vmcnt(0)" ::: "memory");
    }
    __builtin_amdgcn_s_barrier();
    __builtin_amdgcn_s_setprio(1);
    mfma_group<3, MR, NR, NG>(a, b, acc);
    __builtin_amdgcn_s_setprio(0);
    __builtin_amdgcn_s_barrier();
    cur = nb;
  }

  // epilogue
#pragma unroll
  for (int m = 0; m < MR; ++m) {
    const int r0 = tileM + wr * (BM / WM) + m * 16 + lg * 4;
#pragma unroll
    for (int n = 0; n < NR; ++n) {
      const int cc = tileN + wc * (BN / WN) + n * 16 + lr;
#pragma unroll
      for (int r = 0; r < 4; ++r) {
        const size_t o = obase + (size_t)(r0 + r) * ldo + cc;
        const float av = acc[m][n][r];
        if constexpr (EPI == 0) {
          outF[o] = av * scale;
        } else if constexpr (EPI == 1) {
          outF[o] = resid[o] + av;
        } else if constexpr (EPI == 2) {
          const float zz = av + bias[cc];
          outB[o] = f2bf(0.5f * zz * (1.0f + erff(zz * 0.70710678118654752f)));
        } else {
          outF[o] = outF[o] + av + bias[cc];
        }
      }
    }
  }
}

extern "C" void kernel_launch(void* const* d_in, const int* in_sizes, int n_in,
                              void* d_out, int out_size, void* d_ws,
                              size_t ws_size, hipStream_t stream) {
  const float* x = (const float*)d_in[0];
  const float* ln1_g = (const float*)d_in[1];
  const float* ln1_b = (const float*)d_in[2];
  const float* ln2_g = (const float*)d_in[3];
  const float* ln2_b = (const float*)d_in[4];
  const float* W1 = (const float*)d_in[5];
  const float* b1 = (const float*)d_in[6];
  const float* W2 = (const float*)d_in[7];
  const float* b2 = (const float*)d_in[8];
  float* out = (float*)d_out;
  char* ws = (char*)d_ws;

  u16* qk = (u16*)(ws + 0);                         // 16 MB  [B,T,C] bf16 (q == k)
  u16* vv = (u16*)(ws + (16LL << 20));              // 16 MB  [B,T,C] bf16
  u16* vT = (u16*)(ws + (32LL << 20));              // 16 MB  [B,C,T] bf16
  float* S = (float*)(ws + (48LL << 20));           // 64 MB  [B,T,T] fp32 -> bf16 P in-place
  u16* ln2h = (u16*)(ws + 0);                       // reuse qk region
  u16* W1T = (u16*)(ws + (16LL << 20));             // 8 MB   [F,C]
  u16* W2T = (u16*)(ws + (24LL << 20));             // 8 MB   [C,F]
  u16* h1 = (u16*)(ws + (48LL << 20));              // 64 MB  [B*T,F] bf16 (reuse S)

  ln1_rope_k<<<Bb * T, 256, 0, stream>>>(x, ln1_g, ln1_b, qk, vv);
  transp_bf16<<<dim3(C / 32, T / 32, Bb), dim3(32, 8), 0, stream>>>(vv, vT, T, C);

  // S = scale * q . q^T   (M=N=T, K=C, batched) : 256x256 tiles, 8x8x4 = 256 WGs
  gemm8p<256, 256, 4, 2, 0><<<dim3(T / 256, T / 256, Bb), 512, 0, stream>>>(
      qk, qk, C, C, C, (long long)T * C, (long long)T * C, S, nullptr, T,
      (long long)T * T, nullptr, nullptr, 1.f / 32.f);

  softmax_rows<<<Bb * T, 256, 0, stream>>>(S);

  // out = x + P . V   (M=T, N=C, K=T) : 128x256 tiles, 16x4x4 = 256 WGs
  gemm8p<128, 256, 2, 4, 1><<<dim3(C / 256, T / 128, Bb), 512, 0, stream>>>(
      (const u16*)S, vT, 2 * T, T, T, 2LL * T * T, (long long)C * T, out,
      nullptr, C, (long long)T * C, nullptr, x, 1.f);

  ln2_k<<<Bb * T, 256, 0, stream>>>(out, ln2_g, ln2_b, ln2h);
  transp_f32_bf16<<<dim3(F / 32, C / 32, 1), dim3(32, 8), 0, stream>>>(W1, W1T, C, F);
  transp_f32_bf16<<<dim3(C / 32, F / 32, 1), dim3(32, 8), 0, stream>>>(W2, W2T, F, C);

  // h1 = gelu(ln2h . W1 + b1)   (M=B*T, N=F, K=C) : 32x16 = 512 WGs
  gemm8p<256, 256, 4, 2, 2><<<dim3(F / 256, (Bb * T) / 256, 1), 512, 0, stream>>>(
      ln2h, W1T, C, C, C, 0, 0, nullptr, h1, F, 0, b1, nullptr, 1.f);

  // out += h1 . W2 + b2   (M=B*T, N=C, K=F) : 64x4 = 256 WGs
  gemm8p<128, 256, 2, 4, 3><<<dim3(C / 256, (Bb * T) / 128, 1), 512, 0, stream>>>(
      h1, W2T, F, F, F, 0, 0, out, nullptr, C, 0, b2, nullptr, 1.f);
}

// Round 3
// 313.249 us; speedup vs baseline: 1.3539x; 1.1009x over previous
//
#include <hip/hip_runtime.h>

using u16 = unsigned short;
using u32 = unsigned int;

constexpr int Bb = 4, T = 2048, C = 1024, F = 4096;

typedef __attribute__((ext_vector_type(8))) short short8v;
typedef __attribute__((ext_vector_type(4))) float f32x4;

__device__ __forceinline__ u16 f2bf(float f) {
  u32 bits = __builtin_bit_cast(u32, f);
  u32 r = bits + 0x7FFFu + ((bits >> 16) & 1u);
  return (u16)(r >> 16);
}
__device__ __forceinline__ float bf2f(u32 u) {
  u32 b = u << 16;
  return __builtin_bit_cast(float, b);
}

__device__ __forceinline__ void gld16(const u16* g, u16* l) {
  __builtin_amdgcn_global_load_lds(
      (const __attribute__((address_space(1))) u32*)g,
      (__attribute__((address_space(3))) u32*)l, 16, 0, 0);
}

// ---------------- LN1 + RoPE ----------------
__global__ __launch_bounds__(256) void ln1_rope_k(
    const float* __restrict__ x, const float* __restrict__ gw,
    const float* __restrict__ bw, u16* __restrict__ qk, u16* __restrict__ vv) {
  const int row = blockIdx.x;            // b*T + t
  const int t = row & (T - 1);
  const int tid = threadIdx.x;
  const float4 xv = ((const float4*)(x + (size_t)row * C))[tid];
  float s = xv.x + xv.y + xv.z + xv.w;
  float s2 = xv.x * xv.x + xv.y * xv.y + xv.z * xv.z + xv.w * xv.w;
#pragma unroll
  for (int o = 32; o; o >>= 1) { s += __shfl_xor(s, o, 64); s2 += __shfl_xor(s2, o, 64); }
  __shared__ float red[8];
  if ((tid & 63) == 0) { red[(tid >> 6) * 2] = s; red[(tid >> 6) * 2 + 1] = s2; }
  __syncthreads();
  s = red[0] + red[2] + red[4] + red[6];
  s2 = red[1] + red[3] + red[5] + red[7];
  const float mu = s * (1.f / C);
  const float var = s2 * (1.f / C) - mu * mu;
  const float rstd = rsqrtf(var + 1e-5f);
  const float4 gv = ((const float4*)gw)[tid];
  const float4 bv = ((const float4*)bw)[tid];
  float nn[4];
  nn[0] = (xv.x - mu) * rstd * gv.x + bv.x;
  nn[1] = (xv.y - mu) * rstd * gv.y + bv.y;
  nn[2] = (xv.z - mu) * rstd * gv.z + bv.z;
  nn[3] = (xv.w - mu) * rstd * gv.w + bv.w;
  __shared__ float ns[C];
  const int c0 = tid * 4;
  ns[c0] = nn[0]; ns[c0 + 1] = nn[1]; ns[c0 + 2] = nn[2]; ns[c0 + 3] = nn[3];
  uint2 pv;
  pv.x = (u32)f2bf(nn[0]) | ((u32)f2bf(nn[1]) << 16);
  pv.y = (u32)f2bf(nn[2]) | ((u32)f2bf(nn[3]) << 16);
  ((uint2*)(vv + (size_t)row * C))[tid] = pv;
  __syncthreads();
  float o[4];
#pragma unroll
  for (int e = 0; e < 4; e++) {
    const int c = c0 + e;
    const int j = c & (C / 2 - 1);
    const float invf = exp2f((float)j * (-13.287712379549449f / 512.f));
    float sn, cn;
    sincosf((float)t * invf, &sn, &cn);
    const float other = (c < C / 2) ? ns[c + C / 2] : ns[c - C / 2];
    o[e] = (c < C / 2) ? nn[e] * cn - other * sn : nn[e] * cn + other * sn;
  }
  uint2 qv;
  qv.x = (u32)f2bf(o[0]) | ((u32)f2bf(o[1]) << 16);
  qv.y = (u32)f2bf(o[2]) | ((u32)f2bf(o[3]) << 16);
  ((uint2*)(qk + (size_t)row * C))[tid] = qv;
}

// ---------------- LN2 ----------------
__global__ __launch_bounds__(256) void ln2_k(
    const float* __restrict__ xin, const float* __restrict__ gw,
    const float* __restrict__ bw, u16* __restrict__ out) {
  const int row = blockIdx.x;
  const int tid = threadIdx.x;
  const float4 xv = ((const float4*)(xin + (size_t)row * C))[tid];
  float s = xv.x + xv.y + xv.z + xv.w;
  float s2 = xv.x * xv.x + xv.y * xv.y + xv.z * xv.z + xv.w * xv.w;
#pragma unroll
  for (int o = 32; o; o >>= 1) { s += __shfl_xor(s, o, 64); s2 += __shfl_xor(s2, o, 64); }
  __shared__ float red[8];
  if ((tid & 63) == 0) { red[(tid >> 6) * 2] = s; red[(tid >> 6) * 2 + 1] = s2; }
  __syncthreads();
  s = red[0] + red[2] + red[4] + red[6];
  s2 = red[1] + red[3] + red[5] + red[7];
  const float mu = s * (1.f / C);
  const float var = s2 * (1.f / C) - mu * mu;
  const float rstd = rsqrtf(var + 1e-5f);
  const float4 gv = ((const float4*)gw)[tid];
  const float4 bv = ((const float4*)bw)[tid];
  uint2 pv;
  pv.x = (u32)f2bf((xv.x - mu) * rstd * gv.x + bv.x) |
         ((u32)f2bf((xv.y - mu) * rstd * gv.y + bv.y) << 16);
  pv.y = (u32)f2bf((xv.z - mu) * rstd * gv.z + bv.z) |
         ((u32)f2bf((xv.w - mu) * rstd * gv.w + bv.w) << 16);
  ((uint2*)(out + (size_t)row * C))[tid] = pv;
}

// ---------------- row sums of bf16 exp-logits ----------------
__global__ __launch_bounds__(256) void rowsum_k(const u16* __restrict__ E,
                                                float* __restrict__ rs) {
  const u16* row = E + (size_t)blockIdx.x * T;
  const int tid = threadIdx.x;
  const uint4 v = ((const uint4*)row)[tid];
  float s = bf2f(v.x & 0xffffu) + bf2f(v.x >> 16) + bf2f(v.y & 0xffffu) +
            bf2f(v.y >> 16) + bf2f(v.z & 0xffffu) + bf2f(v.z >> 16) +
            bf2f(v.w & 0xffffu) + bf2f(v.w >> 16);
#pragma unroll
  for (int o = 32; o; o >>= 1) s += __shfl_xor(s, o, 64);
  __shared__ float red[4];
  if ((tid & 63) == 0) red[tid >> 6] = s;
  __syncthreads();
  if (tid == 0) rs[blockIdx.x] = red[0] + red[1] + red[2] + red[3];
}

// ---------------- transposes ----------------
__global__ __launch_bounds__(256) void transp_bf16(
    const u16* __restrict__ in, u16* __restrict__ out, int R, int Cd) {
  __shared__ u16 tle[32][33];
  const size_t z = (size_t)blockIdx.z * R * Cd;
  const int c0 = blockIdx.x * 32, r0 = blockIdx.y * 32;
  const int tx = threadIdx.x, ty = threadIdx.y;
#pragma unroll
  for (int j = 0; j < 32; j += 8)
    tle[ty + j][tx] = in[z + (size_t)(r0 + ty + j) * Cd + c0 + tx];
  __syncthreads();
#pragma unroll
  for (int j = 0; j < 32; j += 8)
    out[z + (size_t)(c0 + ty + j) * R + r0 + tx] = tle[tx][ty + j];
}

__global__ __launch_bounds__(256) void transp_f32_bf16(
    const float* __restrict__ in, u16* __restrict__ out, int R, int Cd) {
  __shared__ float tle[32][33];
  const int c0 = blockIdx.x * 32, r0 = blockIdx.y * 32;
  const int tx = threadIdx.x, ty = threadIdx.y;
#pragma unroll
  for (int j = 0; j < 32; j += 8)
    tle[ty + j][tx] = in[(size_t)(r0 + ty + j) * Cd + c0 + tx];
  __syncthreads();
#pragma unroll
  for (int j = 0; j < 32; j += 8)
    out[(size_t)(c0 + ty + j) * R + r0 + tx] = f2bf(tle[tx][ty + j]);
}

// ================= 8-phase 512-thread MFMA GEMM (BT layout) =================
// out[i][j] = sum_k A[i][k] * B[j][k]
// EPI 0: outB = bf16(exp(acc*scale))          (attention exp-logits)
// EPI 1: outF = resid + acc / rowsum[row]     (PV, bias = rowsums[B*T])
// EPI 2: outB = bf16(gelu(acc+bias[col]))
// EPI 3: outF += acc + bias[col]
template <int g, int MR, int NR, int NG>
__device__ __forceinline__ void mfma_group(short8v (&a)[MR][2], short8v (&b)[NR][2],
                                           f32x4 (&acc)[MR][NR]) {
#pragma unroll
  for (int n0 = 0; n0 < NG; ++n0)
#pragma unroll
    for (int m = 0; m < MR; ++m)
#pragma unroll
      for (int kk = 0; kk < 2; ++kk)
        acc[m][g * NG + n0] = __builtin_amdgcn_mfma_f32_16x16x32_bf16(
            a[m][kk], b[g * NG + n0][kk], acc[m][g * NG + n0], 0, 0, 0);
}

template <int BM, int BN, int WM, int WN, int EPI>
__global__ __launch_bounds__(512, 2) void gemm8p(
    const u16* __restrict__ A, const u16* __restrict__ Bm, int lda, int ldb,
    int K, long long strideA, long long strideB, float* __restrict__ outF,
    u16* __restrict__ outB, int ldo, long long strideO,
    const float* __restrict__ bias, const float* __restrict__ resid,
    float scale) {
  constexpr int MR = BM / WM / 16;   // M fragments per wave
  constexpr int NR = BN / WN / 16;   // N fragments per wave
  constexpr int NG = NR / 4;         // N frags per phase-group
  constexpr int LA = BM / 128;       // gld16 per A half-tile per thread
  constexpr int LB = BN / 128;
  constexpr int ABYTES = BM * 128;   // one A buffer (BK=64 bf16 = 128B/row)
  constexpr int BBYTES = BN * 128;
  constexpr int VS = 2 * LA + LB;    // steady-state vmcnt
  static_assert(NR % 4 == 0 && MR * 2 <= 16, "");

  __shared__ alignas(16) char ldsmem[2 * ABYTES + 2 * BBYTES];
  char* const ldsA = ldsmem;
  char* const ldsB = ldsmem + 2 * ABYTES;

  // ---- T1: XCD-aware bijective block swizzle (all grids are multiples of 8)
  const u32 gx = gridDim.x, gy = gridDim.y;
  const u32 nwg = gx * gy * gridDim.z;
  u32 fid = blockIdx.x + gx * (blockIdx.y + gy * blockIdx.z);
  fid = (fid & 7u) * (nwg >> 3) + (fid >> 3);
  const int bidx = fid % gx;
  const u32 fyz = fid / gx;
  const int bidy = fyz % gy;
  const int bz = fyz / gy;

  A += (size_t)bz * strideA;
  Bm += (size_t)bz * strideB;
  const size_t obase = (size_t)bz * strideO;
  const int tileM = bidy * BM, tileN = bidx * BN;
  const int tid = threadIdx.x;
  const int lane = tid & 63, wid = tid >> 6;
  const int wr = wid / WN, wc = wid % WN;
  const int lr = lane & 15, lg = lane >> 4;
  const int aswz = (lr & 7) << 4;    // read-side XOR swizzle (row&7)<<4

  // staging: thread covers 16B at (row = tr, bytecol = (tid&7)*16), source
  // column pre-swizzled so linear LDS dest + swizzled read are consistent.
  const int tr = tid >> 3;
  const int colsw = ((((tid & 7) << 4) ^ ((tr & 7) << 4))) >> 1;  // element col
  const u16* Ab = A + (size_t)(tileM + tr) * lda + colsw;
  const u16* Bbp = Bm + (size_t)(tileN + tr) * ldb + colsw;
  const int NT = K >> 6;  // K-tiles of 64

  auto stageA = [&](int buf, int half, int k0) {
#pragma unroll
    for (int l = 0; l < LA; ++l)
      gld16(Ab + (size_t)(half * (BM / 2) + l * 64) * lda + k0,
            (u16*)&ldsA[buf * ABYTES + (half * (BM / 2) + l * 64) * 128 + tid * 16]);
  };
  auto stageB = [&](int buf, int half, int k0) {
#pragma unroll
    for (int l = 0; l < LB; ++l)
      gld16(Bbp + (size_t)(half * (BN / 2) + l * 64) * ldb + k0,
            (u16*)&ldsB[buf * BBYTES + (half * (BN / 2) + l * 64) * 128 + tid * 16]);
  };

  f32x4 acc[MR][NR];
#pragma unroll
  for (int m = 0; m < MR; ++m)
#pragma unroll
    for (int n = 0; n < NR; ++n) acc[m][n] = (f32x4){0.f, 0.f, 0.f, 0.f};
  short8v a[MR][2], b[NR][2];

  auto readA = [&](int buf) {
#pragma unroll
    for (int m = 0; m < MR; ++m)
#pragma unroll
      for (int kk = 0; kk < 2; ++kk)
        a[m][kk] = *(const short8v*)&ldsA[buf * ABYTES +
            (wr * (BM / WM) + m * 16 + lr) * 128 + ((kk * 64 + lg * 16) ^ aswz)];
  };
  auto readB0 = [&](int buf) {
#pragma unroll
    for (int n = 0; n < NG; ++n)
#pragma unroll
      for (int kk = 0; kk < 2; ++kk)
        b[n][kk] = *(const short8v*)&ldsB[buf * BBYTES +
            (wc * (BN / WN) + n * 16 + lr) * 128 + ((kk * 64 + lg * 16) ^ aswz)];
  };
  auto readB1 = [&](int buf) {
#pragma unroll
    for (int n = NG; n < NR; ++n)
#pragma unroll
      for (int kk = 0; kk < 2; ++kk)
        b[n][kk] = *(const short8v*)&ldsB[buf * BBYTES +
            (wc * (BN / WN) + n * 16 + lr) * 128 + ((kk * 64 + lg * 16) ^ aswz)];
  };

  // prologue: tile0 fully, tile1 {A0,A1,B0}; leaves VS loads in flight
  stageA(0, 0, 0); stageA(0, 1, 0); stageB(0, 0, 0); stageB(0, 1, 0);
  stageA(1, 0, 64); stageA(1, 1, 64); stageB(1, 0, 64);
  if constexpr (VS == 6) asm volatile("s_waitcnt vmcnt(6)" ::: "memory");
  else asm volatile("s_waitcnt vmcnt(4)" ::: "memory");
  __builtin_amdgcn_s_barrier();

  int cur = 0;
  for (int k = 0; k < NT; ++k) {
    const int nb = cur ^ 1;
    const int k1 = (k + 1) << 6, k2 = (k + 2) << 6;
    // ---- phase 0: read A(all)+B(group0); stage B1(k+1) -> other buffer
    readA(cur);
    readB0(cur);
    if (k + 1 < NT) stageB(nb, 1, k1);
    __builtin_amdgcn_s_barrier();
    __builtin_amdgcn_s_setprio(1);
    mfma_group<0, MR, NR, NG>(a, b, acc);
    __builtin_amdgcn_s_setprio(0);
    __builtin_amdgcn_s_barrier();
    // ---- phase 1: read B(rest); stage A0(k+2) -> cur (A region dead)
    readB1(cur);
    if (k + 2 < NT) stageA(cur, 0, k2);
    asm volatile("s_waitcnt lgkmcnt(0)" ::: "memory");  // harden: all B reads done
    __builtin_amdgcn_s_barrier();
    __builtin_amdgcn_s_setprio(1);
    mfma_group<1, MR, NR, NG>(a, b, acc);
    __builtin_amdgcn_s_setprio(0);
    __builtin_amdgcn_s_barrier();
    // ---- phase 2: stage A1(k+2)
    if (k + 2 < NT) stageA(cur, 1, k2);
    __builtin_amdgcn_s_barrier();
    __builtin_amdgcn_s_setprio(1);
    mfma_group<2, MR, NR, NG>(a, b, acc);
    __builtin_amdgcn_s_setprio(0);
    __builtin_amdgcn_s_barrier();
    // ---- phase 3: stage B0(k+2); counted vmcnt -> tile k+1 buffer complete
    if (k + 2 < NT) stageB(cur, 0, k2);
    if (k < NT - 2) {
      if constexpr (VS == 6) asm volatile("s_waitcnt vmcnt(6)" ::: "memory");
      else asm volatile("s_waitcnt vmcnt(4)" ::: "memory");
    } else if (k == NT - 2) {
      asm volatile("s_waitcnt vmcnt(0)" ::: "memory");
    }
    __builtin_amdgcn_s_barrier();
    __builtin_amdgcn_s_setprio(1);
    mfma_group<3, MR, NR, NG>(a, b, acc);
    __builtin_amdgcn_s_setprio(0);
    __builtin_amdgcn_s_barrier();
    cur = nb;
  }

  // epilogue
#pragma unroll
  for (int m = 0; m < MR; ++m) {
    const int r0 = tileM + wr * (BM / WM) + m * 16 + lg * 4;
#pragma unroll
    for (int n = 0; n < NR; ++n) {
      const int cc = tileN + wc * (BN / WN) + n * 16 + lr;
#pragma unroll
      for (int r = 0; r < 4; ++r) {
        const size_t o = obase + (size_t)(r0 + r) * ldo + cc;
        const float av = acc[m][n][r];
        if constexpr (EPI == 0) {
          outB[o] = f2bf(__expf(av * scale));
        } else if constexpr (EPI == 1) {
          outF[o] = resid[o] + av * (1.0f / bias[(size_t)bz * T + r0 + r]);
        } else if constexpr (EPI == 2) {
          const float zz = av + bias[cc];
          outB[o] = f2bf(0.5f * zz * (1.0f + erff(zz * 0.70710678118654752f)));
        } else {
          outF[o] = outF[o] + av + bias[cc];
        }
      }
    }
  }
}

extern "C" void kernel_launch(void* const* d_in, const int* in_sizes, int n_in,
                              void* d_out, int out_size, void* d_ws,
                              size_t ws_size, hipStream_t stream) {
  const float* x = (const float*)d_in[0];
  const float* ln1_g = (const float*)d_in[1];
  const float* ln1_b = (const float*)d_in[2];
  const float* ln2_g = (const float*)d_in[3];
  const float* ln2_b = (const float*)d_in[4];
  const float* W1 = (const float*)d_in[5];
  const float* b1 = (const float*)d_in[6];
  const float* W2 = (const float*)d_in[7];
  const float* b2 = (const float*)d_in[8];
  float* out = (float*)d_out;
  char* ws = (char*)d_ws;

  u16* qk = (u16*)(ws + 0);               // 16 MB [B,T,C] bf16 (q == k); later ln2h
  u16* vv = (u16*)(ws + (16LL << 20));    // 16 MB [B,T,C] bf16 (dead after transp)
  float* rs = (float*)(ws + (16LL << 20));// 32 KB rowsums (vv region, after transp)
  u16* vT = (u16*)(ws + (32LL << 20));    // 16 MB [B,C,T] bf16
  u16* S = (u16*)(ws + (48LL << 20));     // 32 MB [B,T,T] bf16 exp-logits
  u16* ln2h = (u16*)(ws + 0);             // reuse qk region
  u16* W1T = (u16*)(ws + (16LL << 20));   // 8 MB [F,C]   (after PV consumed rs)
  u16* W2T = (u16*)(ws + (24LL << 20));   // 8 MB [C,F]
  u16* h1 = (u16*)(ws + (48LL << 20));    // 64 MB [B*T,F] bf16 (reuse S)

  ln1_rope_k<<<Bb * T, 256, 0, stream>>>(x, ln1_g, ln1_b, qk, vv);
  transp_bf16<<<dim3(C / 32, T / 32, Bb), dim3(32, 8), 0, stream>>>(vv, vT, T, C);

  // S = exp(scale * q . q^T) in bf16  (M=N=T, K=C, batched): 8x8x4 = 256 WGs
  gemm8p<256, 256, 4, 2, 0><<<dim3(T / 256, T / 256, Bb), 512, 0, stream>>>(
      qk, qk, C, C, C, (long long)T * C, (long long)T * C, nullptr, S, T,
      (long long)T * T, nullptr, nullptr, 1.f / 32.f);

  rowsum_k<<<Bb * T, 256, 0, stream>>>(S, rs);

  // out = x + (E . V) / rowsum   (M=T, N=C, K=T): 4x16x4 = 256 WGs
  gemm8p<128, 256, 2, 4, 1><<<dim3(C / 256, T / 128, Bb), 512, 0, stream>>>(
      S, vT, T, T, T, (long long)T * T, (long long)C * T, out,
      nullptr, C, (long long)T * C, rs, x, 1.f);

  ln2_k<<<Bb * T, 256, 0, stream>>>(out, ln2_g, ln2_b, ln2h);
  transp_f32_bf16<<<dim3(F / 32, C / 32, 1), dim3(32, 8), 0, stream>>>(W1, W1T, C, F);
  transp_f32_bf16<<<dim3(C / 32, F / 32, 1), dim3(32, 8), 0, stream>>>(W2, W2T, F, C);

  // h1 = gelu(ln2h . W1 + b1)   (M=B*T, N=F, K=C): 16x32 = 512 WGs
  gemm8p<256, 256, 4, 2, 2><<<dim3(F / 256, (Bb * T) / 256, 1), 512, 0, stream>>>(
      ln2h, W1T, C, C, C, 0, 0, nullptr, h1, F, 0, b1, nullptr, 1.f);

  // out += h1 . W2 + b2   (M=B*T, N=C, K=F): 4x64 = 256 WGs
  gemm8p<128, 256, 2, 4, 3><<<dim3(C / 256, (Bb * T) / 128, 1), 512, 0, stream>>>(
      h1, W2T, F, F, F, 0, 0, out, nullptr, C, 0, b2, nullptr, 1.f);
}

// Round 4
// 289.328 us; speedup vs baseline: 1.4659x; 1.0827x over previous
//
#include <hip/hip_runtime.h>

using u16 = unsigned short;
using u32 = unsigned int;

constexpr int Bb = 4, T = 2048, C = 1024, F = 4096;

typedef __attribute__((ext_vector_type(8))) short short8v;
typedef __attribute__((ext_vector_type(4))) float f32x4;

__device__ __forceinline__ u16 f2bf(float f) {
  u32 bits = __builtin_bit_cast(u32, f);
  u32 r = bits + 0x7FFFu + ((bits >> 16) & 1u);
  return (u16)(r >> 16);
}
__device__ __forceinline__ float bf2f(u32 u) {
  u32 b = u << 16;
  return __builtin_bit_cast(float, b);
}

__device__ __forceinline__ void gld16(const u16* g, u16* l) {
  __builtin_amdgcn_global_load_lds(
      (const __attribute__((address_space(1))) u32*)g,
      (__attribute__((address_space(3))) u32*)l, 16, 0, 0);
}

// ---------------- LN1 + RoPE (+ zero rs) ----------------
__global__ __launch_bounds__(256) void ln1_rope_k(
    const float* __restrict__ x, const float* __restrict__ gw,
    const float* __restrict__ bw, u16* __restrict__ qk, u16* __restrict__ vv,
    float* __restrict__ rs) {
  const int row = blockIdx.x;            // b*T + t
  const int t = row & (T - 1);
  const int tid = threadIdx.x;
  if (tid == 0) rs[row] = 0.f;
  const float4 xv = ((const float4*)(x + (size_t)row * C))[tid];
  float s = xv.x + xv.y + xv.z + xv.w;
  float s2 = xv.x * xv.x + xv.y * xv.y + xv.z * xv.z + xv.w * xv.w;
#pragma unroll
  for (int o = 32; o; o >>= 1) { s += __shfl_xor(s, o, 64); s2 += __shfl_xor(s2, o, 64); }
  __shared__ float red[8];
  if ((tid & 63) == 0) { red[(tid >> 6) * 2] = s; red[(tid >> 6) * 2 + 1] = s2; }
  __syncthreads();
  s = red[0] + red[2] + red[4] + red[6];
  s2 = red[1] + red[3] + red[5] + red[7];
  const float mu = s * (1.f / C);
  const float var = s2 * (1.f / C) - mu * mu;
  const float rstd = rsqrtf(var + 1e-5f);
  const float4 gv = ((const float4*)gw)[tid];
  const float4 bv = ((const float4*)bw)[tid];
  float nn[4];
  nn[0] = (xv.x - mu) * rstd * gv.x + bv.x;
  nn[1] = (xv.y - mu) * rstd * gv.y + bv.y;
  nn[2] = (xv.z - mu) * rstd * gv.z + bv.z;
  nn[3] = (xv.w - mu) * rstd * gv.w + bv.w;
  __shared__ float ns[C];
  const int c0 = tid * 4;
  ns[c0] = nn[0]; ns[c0 + 1] = nn[1]; ns[c0 + 2] = nn[2]; ns[c0 + 3] = nn[3];
  uint2 pv;
  pv.x = (u32)f2bf(nn[0]) | ((u32)f2bf(nn[1]) << 16);
  pv.y = (u32)f2bf(nn[2]) | ((u32)f2bf(nn[3]) << 16);
  ((uint2*)(vv + (size_t)row * C))[tid] = pv;
  __syncthreads();
  float o[4];
#pragma unroll
  for (int e = 0; e < 4; e++) {
    const int c = c0 + e;
    const int j = c & (C / 2 - 1);
    const float invf = exp2f((float)j * (-13.287712379549449f / 512.f));
    float sn, cn;
    __sincosf((float)t * invf, &sn, &cn);
    const float other = (c < C / 2) ? ns[c + C / 2] : ns[c - C / 2];
    o[e] = (c < C / 2) ? nn[e] * cn - other * sn : nn[e] * cn + other * sn;
  }
  uint2 qv;
  qv.x = (u32)f2bf(o[0]) | ((u32)f2bf(o[1]) << 16);
  qv.y = (u32)f2bf(o[2]) | ((u32)f2bf(o[3]) << 16);
  ((uint2*)(qk + (size_t)row * C))[tid] = qv;
}

// ---------------- LN2 ----------------
__global__ __launch_bounds__(256) void ln2_k(
    const float* __restrict__ xin, const float* __restrict__ gw,
    const float* __restrict__ bw, u16* __restrict__ out) {
  const int row = blockIdx.x;
  const int tid = threadIdx.x;
  const float4 xv = ((const float4*)(xin + (size_t)row * C))[tid];
  float s = xv.x + xv.y + xv.z + xv.w;
  float s2 = xv.x * xv.x + xv.y * xv.y + xv.z * xv.z + xv.w * xv.w;
#pragma unroll
  for (int o = 32; o; o >>= 1) { s += __shfl_xor(s, o, 64); s2 += __shfl_xor(s2, o, 64); }
  __shared__ float red[8];
  if ((tid & 63) == 0) { red[(tid >> 6) * 2] = s; red[(tid >> 6) * 2 + 1] = s2; }
  __syncthreads();
  s = red[0] + red[2] + red[4] + red[6];
  s2 = red[1] + red[3] + red[5] + red[7];
  const float mu = s * (1.f / C);
  const float var = s2 * (1.f / C) - mu * mu;
  const float rstd = rsqrtf(var + 1e-5f);
  const float4 gv = ((const float4*)gw)[tid];
  const float4 bv = ((const float4*)bw)[tid];
  uint2 pv;
  pv.x = (u32)f2bf((xv.x - mu) * rstd * gv.x + bv.x) |
         ((u32)f2bf((xv.y - mu) * rstd * gv.y + bv.y) << 16);
  pv.y = (u32)f2bf((xv.z - mu) * rstd * gv.z + bv.z) |
         ((u32)f2bf((xv.w - mu) * rstd * gv.w + bv.w) << 16);
  ((uint2*)(out + (size_t)row * C))[tid] = pv;
}

// ---------------- transposes ----------------
__global__ __launch_bounds__(256) void transp_bf16(
    const u16* __restrict__ in, u16* __restrict__ out, int R, int Cd) {
  __shared__ u16 tle[32][33];
  const size_t z = (size_t)blockIdx.z * R * Cd;
  const int c0 = blockIdx.x * 32, r0 = blockIdx.y * 32;
  const int tx = threadIdx.x, ty = threadIdx.y;
#pragma unroll
  for (int j = 0; j < 32; j += 8)
    tle[ty + j][tx] = in[z + (size_t)(r0 + ty + j) * Cd + c0 + tx];
  __syncthreads();
#pragma unroll
  for (int j = 0; j < 32; j += 8)
    out[z + (size_t)(c0 + ty + j) * R + r0 + tx] = tle[tx][ty + j];
}

__global__ __launch_bounds__(256) void transp_f32_bf16(
    const float* __restrict__ in, u16* __restrict__ out, int R, int Cd) {
  __shared__ float tle[32][33];
  const int c0 = blockIdx.x * 32, r0 = blockIdx.y * 32;
  const int tx = threadIdx.x, ty = threadIdx.y;
#pragma unroll
  for (int j = 0; j < 32; j += 8)
    tle[ty + j][tx] = in[(size_t)(r0 + ty + j) * Cd + c0 + tx];
  __syncthreads();
#pragma unroll
  for (int j = 0; j < 32; j += 8)
    out[(size_t)(c0 + ty + j) * R + r0 + tx] = f2bf(tle[tx][ty + j]);
}

// ================= 2-barrier/K-tile MFMA GEMM (BT layout) =================
// out[i][j] = sum_k A[i][k] * B[j][k]
// EPI 0: outB = bf16(exp(acc*scale)); atomic row-sums into bias[]
// EPI 1: outF = resid + acc / bias[row]
// EPI 2: outB = bf16(gelu(acc+bias[col]))
// EPI 3: outF += acc + bias[col]
template <int g, int MR, int NR, int NG>
__device__ __forceinline__ void mfma_group(short8v (&a)[MR][2], short8v (&b)[NR][2],
                                           f32x4 (&acc)[MR][NR]) {
#pragma unroll
  for (int n0 = 0; n0 < NG; ++n0)
#pragma unroll
    for (int m = 0; m < MR; ++m)
#pragma unroll
      for (int kk = 0; kk < 2; ++kk)
        acc[m][g * NG + n0] = __builtin_amdgcn_mfma_f32_16x16x32_bf16(
            a[m][kk], b[g * NG + n0][kk], acc[m][g * NG + n0], 0, 0, 0);
}

template <int BM, int BN, int WM, int WN, int EPI>
__global__ __launch_bounds__(512, 2) void gemm8p(
    const u16* __restrict__ A, const u16* __restrict__ Bm, int lda, int ldb,
    int K, long long strideA, long long strideB, float* __restrict__ outF,
    u16* __restrict__ outB, int ldo, long long strideO,
    float* __restrict__ bias, const float* __restrict__ resid, float scale) {
  constexpr int MR = BM / WM / 16;   // M fragments per wave
  constexpr int NR = BN / WN / 16;   // N fragments per wave
  constexpr int NG = NR / 4;         // N frags per phase-group
  constexpr int LA = BM / 128;       // gld16 per A half-tile per thread
  constexpr int LB = BN / 128;
  constexpr int ABYTES = BM * 128;   // one A buffer (BK=64 bf16 = 128B/row)
  constexpr int BBYTES = BN * 128;
  constexpr int VS = 2 * LA + LB;    // steady-state vmcnt
  static_assert(NR % 4 == 0 && MR * 2 <= 16, "");

  __shared__ alignas(16) char ldsmem[2 * ABYTES + 2 * BBYTES];
  char* const ldsA = ldsmem;
  char* const ldsB = ldsmem + 2 * ABYTES;

  // ---- T1: XCD-aware bijective block swizzle (all grids are multiples of 8)
  const u32 gx = gridDim.x, gy = gridDim.y;
  const u32 nwg = gx * gy * gridDim.z;
  u32 fid = blockIdx.x + gx * (blockIdx.y + gy * blockIdx.z);
  fid = (fid & 7u) * (nwg >> 3) + (fid >> 3);
  const int bidx = fid % gx;
  const u32 fyz = fid / gx;
  const int bidy = fyz % gy;
  const int bz = fyz / gy;

  A += (size_t)bz * strideA;
  Bm += (size_t)bz * strideB;
  const size_t obase = (size_t)bz * strideO;
  const int tileM = bidy * BM, tileN = bidx * BN;
  const int tid = threadIdx.x;
  const int lane = tid & 63, wid = tid >> 6;
  const int wr = wid / WN, wc = wid % WN;
  const int lr = lane & 15, lg = lane >> 4;
  const int aswz = (lr & 7) << 4;    // read-side XOR swizzle (row&7)<<4

  // staging: thread covers 16B at (row = tr, bytecol = (tid&7)*16), source
  // column pre-swizzled so linear LDS dest + swizzled read are consistent.
  const int tr = tid >> 3;
  const int colsw = ((((tid & 7) << 4) ^ ((tr & 7) << 4))) >> 1;  // element col
  const u16* Ab = A + (size_t)(tileM + tr) * lda + colsw;
  const u16* Bbp = Bm + (size_t)(tileN + tr) * ldb + colsw;
  const int NT = K >> 6;  // K-tiles of 64

  auto stageA = [&](int buf, int half, int k0) {
#pragma unroll
    for (int l = 0; l < LA; ++l)
      gld16(Ab + (size_t)(half * (BM / 2) + l * 64) * lda + k0,
            (u16*)&ldsA[buf * ABYTES + (half * (BM / 2) + l * 64) * 128 + tid * 16]);
  };
  auto stageB = [&](int buf, int half, int k0) {
#pragma unroll
    for (int l = 0; l < LB; ++l)
      gld16(Bbp + (size_t)(half * (BN / 2) + l * 64) * ldb + k0,
            (u16*)&ldsB[buf * BBYTES + (half * (BN / 2) + l * 64) * 128 + tid * 16]);
  };

  f32x4 acc[MR][NR];
#pragma unroll
  for (int m = 0; m < MR; ++m)
#pragma unroll
    for (int n = 0; n < NR; ++n) acc[m][n] = (f32x4){0.f, 0.f, 0.f, 0.f};
  short8v a[MR][2], b[NR][2];

  auto readA = [&](int buf) {
#pragma unroll
    for (int m = 0; m < MR; ++m)
#pragma unroll
      for (int kk = 0; kk < 2; ++kk)
        a[m][kk] = *(const short8v*)&ldsA[buf * ABYTES +
            (wr * (BM / WM) + m * 16 + lr) * 128 + ((kk * 64 + lg * 16) ^ aswz)];
  };
  auto readB = [&](int buf) {
#pragma unroll
    for (int n = 0; n < NR; ++n)
#pragma unroll
      for (int kk = 0; kk < 2; ++kk)
        b[n][kk] = *(const short8v*)&ldsB[buf * BBYTES +
            (wc * (BN / WN) + n * 16 + lr) * 128 + ((kk * 64 + lg * 16) ^ aswz)];
  };

  // prologue: tile0 fully, tile1 {A0,A1,B0}; wait tile0 (VS loads stay in flight)
  stageA(0, 0, 0); stageA(0, 1, 0); stageB(0, 0, 0); stageB(0, 1, 0);
  stageA(1, 0, 64); stageA(1, 1, 64); stageB(1, 0, 64);
  if constexpr (VS == 6) asm volatile("s_waitcnt vmcnt(6)" ::: "memory");
  else asm volatile("s_waitcnt vmcnt(4)" ::: "memory");
  __builtin_amdgcn_s_barrier();

  int cur = 0;
  for (int k = 0; k < NT; ++k) {
    const int nb = cur ^ 1;
    const int k1 = (k + 1) << 6, k2 = (k + 2) << 6;
    // issue ALL fragment reads for this tile; compiler inserts counted lgkmcnt
    // per first use, so MFMA g0/g1 overlap the in-flight reads for g2/g3.
    readA(cur);
    readB(cur);
    if (k + 1 < NT) stageB(nb, 1, k1);   // finish tile k+1 staging (B1 half)
    __builtin_amdgcn_s_setprio(1);
    mfma_group<0, MR, NR, NG>(a, b, acc);
    mfma_group<1, MR, NR, NG>(a, b, acc);
    __builtin_amdgcn_s_setprio(0);
    // own reads of cur complete; barrier joins all waves -> cur buffer dead
    asm volatile("s_waitcnt lgkmcnt(0)" ::: "memory");
    __builtin_amdgcn_s_barrier();
    // stage tile k+2 into cur (now free); its loads hide under g2/g3 MFMA
    if (k + 2 < NT) { stageA(cur, 0, k2); stageA(cur, 1, k2); stageB(cur, 0, k2); }
    __builtin_amdgcn_s_setprio(1);
    mfma_group<2, MR, NR, NG>(a, b, acc);
    mfma_group<3, MR, NR, NG>(a, b, acc);
    __builtin_amdgcn_s_setprio(0);
    // counted vmcnt: everything except tile k+2's (2LA+LB) loads has landed,
    // i.e. tile k+1 (buffer nb) is complete; barrier joins all waves.
    if (k < NT - 2) {
      if constexpr (VS == 6) asm volatile("s_waitcnt vmcnt(6)" ::: "memory");
      else asm volatile("s_waitcnt vmcnt(4)" ::: "memory");
    } else if (k == NT - 2) {
      asm volatile("s_waitcnt vmcnt(0)" ::: "memory");
    }
    __builtin_amdgcn_s_barrier();
    cur = nb;
  }

  // epilogue
  if constexpr (EPI == 0) {
#pragma unroll
    for (int m = 0; m < MR; ++m) {
      const int r0 = tileM + wr * (BM / WM) + m * 16 + lg * 4;
      float psum[4] = {0.f, 0.f, 0.f, 0.f};
#pragma unroll
      for (int n = 0; n < NR; ++n) {
        const int cc = tileN + wc * (BN / WN) + n * 16 + lr;
#pragma unroll
        for (int r = 0; r < 4; ++r) {
          const u16 h = f2bf(__expf(acc[m][n][r] * scale));
          outB[obase + (size_t)(r0 + r) * ldo + cc] = h;
          psum[r] += bf2f(h);
        }
      }
#pragma unroll
      for (int r = 0; r < 4; ++r) {
        float v = psum[r];
        v += __shfl_xor(v, 1, 64); v += __shfl_xor(v, 2, 64);
        v += __shfl_xor(v, 4, 64); v += __shfl_xor(v, 8, 64);
        if (lr == 0) atomicAdd(&bias[(size_t)bz * T + r0 + r], v);
      }
    }
  } else {
#pragma unroll
    for (int m = 0; m < MR; ++m) {
      const int r0 = tileM + wr * (BM / WM) + m * 16 + lg * 4;
#pragma unroll
      for (int n = 0; n < NR; ++n) {
        const int cc = tileN + wc * (BN / WN) + n * 16 + lr;
#pragma unroll
        for (int r = 0; r < 4; ++r) {
          const size_t o = obase + (size_t)(r0 + r) * ldo + cc;
          const float av = acc[m][n][r];
          if constexpr (EPI == 1) {
            outF[o] = resid[o] + av * (1.0f / bias[(size_t)bz * T + r0 + r]);
          } else if constexpr (EPI == 2) {
            const float zz = av + bias[cc];
            outB[o] = f2bf(0.5f * zz * (1.0f + erff(zz * 0.70710678118654752f)));
          } else {
            outF[o] = outF[o] + av + bias[cc];
          }
        }
      }
    }
  }
}

extern "C" void kernel_launch(void* const* d_in, const int* in_sizes, int n_in,
                              void* d_out, int out_size, void* d_ws,
                              size_t ws_size, hipStream_t stream) {
  const float* x = (const float*)d_in[0];
  const float* ln1_g = (const float*)d_in[1];
  const float* ln1_b = (const float*)d_in[2];
  const float* ln2_g = (const float*)d_in[3];
  const float* ln2_b = (const float*)d_in[4];
  const float* W1 = (const float*)d_in[5];
  const float* b1 = (const float*)d_in[6];
  const float* W2 = (const float*)d_in[7];
  const float* b2 = (const float*)d_in[8];
  float* out = (float*)d_out;
  char* ws = (char*)d_ws;

  u16* qk = (u16*)(ws + 0);               // 16 MB [B,T,C] bf16 (q == k); later ln2h
  u16* vv = (u16*)(ws + (16LL << 20));    // 16 MB [B,T,C] bf16 (dead after transp)
  u16* vT = (u16*)(ws + (32LL << 20));    // 16 MB [B,C,T] bf16
  u16* S = (u16*)(ws + (48LL << 20));     // 32 MB [B,T,T] bf16 exp-logits
  float* rs = (float*)(ws + (80LL << 20));// 32 KB rowsums (inside h1's later region)
  u16* ln2h = (u16*)(ws + 0);             // reuse qk region
  u16* W1T = (u16*)(ws + (16LL << 20));   // 8 MB [F,C]
  u16* W2T = (u16*)(ws + (24LL << 20));   // 8 MB [C,F]
  u16* h1 = (u16*)(ws + (48LL << 20));    // 64 MB [B*T,F] bf16 (reuse S + rs)

  ln1_rope_k<<<Bb * T, 256, 0, stream>>>(x, ln1_g, ln1_b, qk, vv, rs);
  transp_bf16<<<dim3(C / 32, T / 32, Bb), dim3(32, 8), 0, stream>>>(vv, vT, T, C);

  // S = exp(scale * q . q^T) bf16, rowsums -> rs (M=N=T, K=C): 8x8x4 = 256 WGs
  gemm8p<256, 256, 4, 2, 0><<<dim3(T / 256, T / 256, Bb), 512, 0, stream>>>(
      qk, qk, C, C, C, (long long)T * C, (long long)T * C, nullptr, S, T,
      (long long)T * T, rs, nullptr, 1.f / 32.f);

  // out = x + (E . V) / rowsum   (M=T, N=C, K=T): 4x16x4 = 256 WGs
  gemm8p<128, 256, 2, 4, 1><<<dim3(C / 256, T / 128, Bb), 512, 0, stream>>>(
      S, vT, T, T, T, (long long)T * T, (long long)C * T, out,
      nullptr, C, (long long)T * C, rs, x, 1.f);

  ln2_k<<<Bb * T, 256, 0, stream>>>(out, ln2_g, ln2_b, ln2h);
  transp_f32_bf16<<<dim3(F / 32, C / 32, 1), dim3(32, 8), 0, stream>>>(W1, W1T, C, F);
  transp_f32_bf16<<<dim3(C / 32, F / 32, 1), dim3(32, 8), 0, stream>>>(W2, W2T, F, C);

  // h1 = gelu(ln2h . W1 + b1)   (M=B*T, N=F, K=C): 16x32 = 512 WGs
  gemm8p<256, 256, 4, 2, 2><<<dim3(F / 256, (Bb * T) / 256, 1), 512, 0, stream>>>(
      ln2h, W1T, C, C, C, 0, 0, nullptr, h1, F, 0, (float*)b1, nullptr, 1.f);

  // out += h1 . W2 + b2   (M=B*T, N=C, K=F): 4x64 = 256 WGs
  gemm8p<128, 256, 2, 4, 3><<<dim3(C / 256, (Bb * T) / 128, 1), 512, 0, stream>>>(
      h1, W2T, F, F, F, 0, 0, out, nullptr, C, 0, (float*)b2, nullptr, 1.f);
}

// Round 5
// 272.565 us; speedup vs baseline: 1.5560x; 1.0615x over previous
//
#include <hip/hip_runtime.h>

using u16 = unsigned short;
using u32 = unsigned int;

constexpr int Bb = 4, T = 2048, C = 1024, F = 4096;

typedef __attribute__((ext_vector_type(8))) short short8v;
typedef __attribute__((ext_vector_type(4))) float f32x4;

__device__ __forceinline__ u16 f2bf(float f) {
  u32 bits = __builtin_bit_cast(u32, f);
  u32 r = bits + 0x7FFFu + ((bits >> 16) & 1u);
  return (u16)(r >> 16);
}
__device__ __forceinline__ float bf2f(u32 u) {
  u32 b = u << 16;
  return __builtin_bit_cast(float, b);
}

__device__ __forceinline__ void gld16(const u16* g, u16* l) {
  __builtin_amdgcn_global_load_lds(
      (const __attribute__((address_space(1))) u32*)g,
      (__attribute__((address_space(3))) u32*)l, 16, 0, 0);
}

// ---------------- LN1 + RoPE: one block per t, all batches (trig once) ------
__global__ __launch_bounds__(256) void ln1_rope_k(
    const float* __restrict__ x, const float* __restrict__ gw,
    const float* __restrict__ bw, u16* __restrict__ qk, u16* __restrict__ vv,
    float* __restrict__ rs) {
  const int t = blockIdx.x;
  const int tid = threadIdx.x;
  if (tid < Bb) rs[(size_t)tid * T + t] = 0.f;
  const int c0 = tid * 4;
  float sn[4], cn[4];
#pragma unroll
  for (int e = 0; e < 4; e++) {
    const int j = (c0 + e) & (C / 2 - 1);
    const float invf = exp2f((float)j * (-13.287712379549449f / 512.f));
    __sincosf((float)t * invf, &sn[e], &cn[e]);
  }
  const float4 gv = ((const float4*)gw)[tid];
  const float4 bv = ((const float4*)bw)[tid];
  __shared__ float ns[C];
  __shared__ float red[8];
  for (int b = 0; b < Bb; b++) {
    const size_t row = (size_t)b * T + t;
    const float4 xv = ((const float4*)(x + row * C))[tid];
    float s = xv.x + xv.y + xv.z + xv.w;
    float s2 = xv.x * xv.x + xv.y * xv.y + xv.z * xv.z + xv.w * xv.w;
#pragma unroll
    for (int o = 32; o; o >>= 1) { s += __shfl_xor(s, o, 64); s2 += __shfl_xor(s2, o, 64); }
    if ((tid & 63) == 0) { red[(tid >> 6) * 2] = s; red[(tid >> 6) * 2 + 1] = s2; }
    __syncthreads();
    s = red[0] + red[2] + red[4] + red[6];
    s2 = red[1] + red[3] + red[5] + red[7];
    const float mu = s * (1.f / C);
    const float var = s2 * (1.f / C) - mu * mu;
    const float rstd = rsqrtf(var + 1e-5f);
    float nn[4];
    nn[0] = (xv.x - mu) * rstd * gv.x + bv.x;
    nn[1] = (xv.y - mu) * rstd * gv.y + bv.y;
    nn[2] = (xv.z - mu) * rstd * gv.z + bv.z;
    nn[3] = (xv.w - mu) * rstd * gv.w + bv.w;
    ns[c0] = nn[0]; ns[c0 + 1] = nn[1]; ns[c0 + 2] = nn[2]; ns[c0 + 3] = nn[3];
    uint2 pv;
    pv.x = (u32)f2bf(nn[0]) | ((u32)f2bf(nn[1]) << 16);
    pv.y = (u32)f2bf(nn[2]) | ((u32)f2bf(nn[3]) << 16);
    ((uint2*)(vv + row * C))[tid] = pv;
    __syncthreads();
    float o[4];
#pragma unroll
    for (int e = 0; e < 4; e++) {
      const int c = c0 + e;
      const float other = (c < C / 2) ? ns[c + C / 2] : ns[c - C / 2];
      o[e] = (c < C / 2) ? nn[e] * cn[e] - other * sn[e]
                         : nn[e] * cn[e] + other * sn[e];
    }
    uint2 qv;
    qv.x = (u32)f2bf(o[0]) | ((u32)f2bf(o[1]) << 16);
    qv.y = (u32)f2bf(o[2]) | ((u32)f2bf(o[3]) << 16);
    ((uint2*)(qk + row * C))[tid] = qv;
    __syncthreads();  // protect ns/red before next batch
  }
}

// ---------------- LN2 ----------------
__global__ __launch_bounds__(256) void ln2_k(
    const float* __restrict__ xin, const float* __restrict__ gw,
    const float* __restrict__ bw, u16* __restrict__ out) {
  const int row = blockIdx.x;
  const int tid = threadIdx.x;
  const float4 xv = ((const float4*)(xin + (size_t)row * C))[tid];
  float s = xv.x + xv.y + xv.z + xv.w;
  float s2 = xv.x * xv.x + xv.y * xv.y + xv.z * xv.z + xv.w * xv.w;
#pragma unroll
  for (int o = 32; o; o >>= 1) { s += __shfl_xor(s, o, 64); s2 += __shfl_xor(s2, o, 64); }
  __shared__ float red[8];
  if ((tid & 63) == 0) { red[(tid >> 6) * 2] = s; red[(tid >> 6) * 2 + 1] = s2; }
  __syncthreads();
  s = red[0] + red[2] + red[4] + red[6];
  s2 = red[1] + red[3] + red[5] + red[7];
  const float mu = s * (1.f / C);
  const float var = s2 * (1.f / C) - mu * mu;
  const float rstd = rsqrtf(var + 1e-5f);
  const float4 gv = ((const float4*)gw)[tid];
  const float4 bv = ((const float4*)bw)[tid];
  uint2 pv;
  pv.x = (u32)f2bf((xv.x - mu) * rstd * gv.x + bv.x) |
         ((u32)f2bf((xv.y - mu) * rstd * gv.y + bv.y) << 16);
  pv.y = (u32)f2bf((xv.z - mu) * rstd * gv.z + bv.z) |
         ((u32)f2bf((xv.w - mu) * rstd * gv.w + bv.w) << 16);
  ((uint2*)(out + (size_t)row * C))[tid] = pv;
}

// ---------------- transposes ----------------
__global__ __launch_bounds__(256) void transp_bf16(
    const u16* __restrict__ in, u16* __restrict__ out, int R, int Cd) {
  __shared__ u16 tle[32][33];
  const size_t z = (size_t)blockIdx.z * R * Cd;
  const int c0 = blockIdx.x * 32, r0 = blockIdx.y * 32;
  const int tx = threadIdx.x, ty = threadIdx.y;
#pragma unroll
  for (int j = 0; j < 32; j += 8)
    tle[ty + j][tx] = in[z + (size_t)(r0 + ty + j) * Cd + c0 + tx];
  __syncthreads();
#pragma unroll
  for (int j = 0; j < 32; j += 8)
    out[z + (size_t)(c0 + ty + j) * R + r0 + tx] = tle[tx][ty + j];
}

__global__ __launch_bounds__(256) void transp_f32_bf16(
    const float* __restrict__ in, u16* __restrict__ out, int R, int Cd) {
  __shared__ float tle[32][33];
  const int c0 = blockIdx.x * 32, r0 = blockIdx.y * 32;
  const int tx = threadIdx.x, ty = threadIdx.y;
#pragma unroll
  for (int j = 0; j < 32; j += 8)
    tle[ty + j][tx] = in[(size_t)(r0 + ty + j) * Cd + c0 + tx];
  __syncthreads();
#pragma unroll
  for (int j = 0; j < 32; j += 8)
    out[(size_t)(c0 + ty + j) * R + r0 + tx] = f2bf(tle[tx][ty + j]);
}

// ========== 2-barrier/K-tile MFMA GEMM, LDS-read-balanced (BT layout) =======
// out[i][j] = sum_k A[i][k] * B[j][k]
// EPI 0: outB = bf16(exp(acc*scale)); atomic row-sums into bias[]
// EPI 1: outF = resid + acc / bias[row]
// EPI 2: outB = bf16(gelu_tanh(acc+bias[col]))
// EPI 3: outF += acc + bias[col]
template <int g, int MR, int NR, int NG>
__device__ __forceinline__ void mfma_group(short8v (&a)[MR][2], short8v (&b)[NR][2],
                                           f32x4 (&acc)[MR][NR]) {
#pragma unroll
  for (int n0 = 0; n0 < NG; ++n0)
#pragma unroll
    for (int m = 0; m < MR; ++m)
#pragma unroll
      for (int kk = 0; kk < 2; ++kk)
        acc[m][g * NG + n0] = __builtin_amdgcn_mfma_f32_16x16x32_bf16(
            a[m][kk], b[g * NG + n0][kk], acc[m][g * NG + n0], 0, 0, 0);
}

template <int BM, int BN, int WM, int WN, int EPI>
__global__ __launch_bounds__(512, 2) void gemm8p(
    const u16* __restrict__ A, const u16* __restrict__ Bm, int lda, int ldb,
    int K, long long strideA, long long strideB, float* __restrict__ outF,
    u16* __restrict__ outB, int ldo, long long strideO,
    float* __restrict__ bias, const float* __restrict__ resid, float scale) {
  constexpr int MR = BM / WM / 16;   // M fragments per wave
  constexpr int NR = BN / WN / 16;   // N fragments per wave
  constexpr int NG = NR / 4;         // N frags per phase-group
  constexpr int LA = BM / 128;       // gld16 per A half-tile per thread
  constexpr int LB = BN / 128;
  constexpr int ABYTES = BM * 128;   // one A buffer (BK=64 bf16 = 128B/row)
  constexpr int BBYTES = BN * 128;
  constexpr int VS = 2 * LA + LB;    // steady-state vmcnt
  static_assert(NR % 4 == 0 && MR * 2 <= 16, "");

  __shared__ alignas(16) char ldsmem[2 * ABYTES + 2 * BBYTES];
  char* const ldsA = ldsmem;
  char* const ldsB = ldsmem + 2 * ABYTES;

  // ---- T1: XCD-aware bijective block swizzle (all grids are multiples of 8)
  const u32 gx = gridDim.x, gy = gridDim.y;
  const u32 nwg = gx * gy * gridDim.z;
  u32 fid = blockIdx.x + gx * (blockIdx.y + gy * blockIdx.z);
  fid = (fid & 7u) * (nwg >> 3) + (fid >> 3);
  const int bidx = fid % gx;
  const u32 fyz = fid / gx;
  const int bidy = fyz % gy;
  const int bz = fyz / gy;

  A += (size_t)bz * strideA;
  Bm += (size_t)bz * strideB;
  const size_t obase = (size_t)bz * strideO;
  const int tileM = bidy * BM, tileN = bidx * BN;
  const int tid = threadIdx.x;
  const int lane = tid & 63, wid = tid >> 6;
  const int wr = wid / WN, wc = wid % WN;
  const int lr = lane & 15, lg = lane >> 4;
  const int aswz = (lr & 7) << 4;    // read-side XOR swizzle (row&7)<<4

  // staging: thread covers 16B at (row = tr, bytecol = (tid&7)*16), source
  // column pre-swizzled so linear LDS dest + swizzled read are consistent.
  const int tr = tid >> 3;
  const int colsw = ((((tid & 7) << 4) ^ ((tr & 7) << 4))) >> 1;  // element col
  const u16* Ab = A + (size_t)(tileM + tr) * lda + colsw;
  const u16* Bbp = Bm + (size_t)(tileN + tr) * ldb + colsw;
  const int NT = K >> 6;  // K-tiles of 64

  auto stageA = [&](int buf, int half, int k0) {
#pragma unroll
    for (int l = 0; l < LA; ++l)
      gld16(Ab + (size_t)(half * (BM / 2) + l * 64) * lda + k0,
            (u16*)&ldsA[buf * ABYTES + (half * (BM / 2) + l * 64) * 128 + tid * 16]);
  };
  auto stageB = [&](int buf, int half, int k0) {
#pragma unroll
    for (int l = 0; l < LB; ++l)
      gld16(Bbp + (size_t)(half * (BN / 2) + l * 64) * ldb + k0,
            (u16*)&ldsB[buf * BBYTES + (half * (BN / 2) + l * 64) * 128 + tid * 16]);
  };

  f32x4 acc[MR][NR];
#pragma unroll
  for (int m = 0; m < MR; ++m)
#pragma unroll
    for (int n = 0; n < NR; ++n) acc[m][n] = (f32x4){0.f, 0.f, 0.f, 0.f};
  short8v a[MR][2], b[NR][2];

  auto readA = [&](int buf) {
#pragma unroll
    for (int m = 0; m < MR; ++m)
#pragma unroll
      for (int kk = 0; kk < 2; ++kk)
        a[m][kk] = *(const short8v*)&ldsA[buf * ABYTES +
            (wr * (BM / WM) + m * 16 + lr) * 128 + ((kk * 64 + lg * 16) ^ aswz)];
  };
  auto readBlo = [&](int buf) {
#pragma unroll
    for (int n = 0; n < NR / 2; ++n)
#pragma unroll
      for (int kk = 0; kk < 2; ++kk)
        b[n][kk] = *(const short8v*)&ldsB[buf * BBYTES +
            (wc * (BN / WN) + n * 16 + lr) * 128 + ((kk * 64 + lg * 16) ^ aswz)];
  };
  auto readBhi = [&](int buf) {
#pragma unroll
    for (int n = NR / 2; n < NR; ++n)
#pragma unroll
      for (int kk = 0; kk < 2; ++kk)
        b[n][kk] = *(const short8v*)&ldsB[buf * BBYTES +
            (wc * (BN / WN) + n * 16 + lr) * 128 + ((kk * 64 + lg * 16) ^ aswz)];
  };

  // prologue: tile0 fully, tile1 {A0,A1,B0}; wait tile0 (VS loads stay in flight)
  stageA(0, 0, 0); stageA(0, 1, 0); stageB(0, 0, 0); stageB(0, 1, 0);
  stageA(1, 0, 64); stageA(1, 1, 64); stageB(1, 0, 64);
  if constexpr (VS == 6) asm volatile("s_waitcnt vmcnt(6)" ::: "memory");
  else asm volatile("s_waitcnt vmcnt(4)" ::: "memory");
  __builtin_amdgcn_s_barrier();

  int cur = 0;
  for (int k = 0; k < NT; ++k) {
    const int nb = cur ^ 1;
    const int k1 = (k + 1) << 6, k2 = (k + 2) << 6;
    // ---- half 0: read A(8) + B-lo(NR reads); MFMA g0,g1 (uses only A+Blo)
    readA(cur);
    readBlo(cur);
    if (k + 1 < NT) stageB(nb, 1, k1);   // finish tile k+1 staging (B1 half)
    __builtin_amdgcn_s_setprio(1);
    mfma_group<0, MR, NR, NG>(a, b, acc);
    mfma_group<1, MR, NR, NG>(a, b, acc);
    __builtin_amdgcn_s_setprio(0);
    // own A+Blo reads done; barrier joins -> A region + B rows [0,BN/2) dead
    asm volatile("s_waitcnt lgkmcnt(0)" ::: "memory");
    __builtin_amdgcn_s_barrier();
    // ---- half 1: read B-hi (rows [BN/2,BN) still live & untouched);
    //      stage k+2 into dead regions; MFMA g2,g3
    readBhi(cur);
    if (k + 2 < NT) { stageA(cur, 0, k2); stageA(cur, 1, k2); stageB(cur, 0, k2); }
    __builtin_amdgcn_s_setprio(1);
    mfma_group<2, MR, NR, NG>(a, b, acc);
    mfma_group<3, MR, NR, NG>(a, b, acc);
    __builtin_amdgcn_s_setprio(0);
    // B-hi reads drained (next iter stages B1 -> cur rows [BN/2,BN));
    // counted vmcnt: only tile k+2's VS loads outstanding -> tile k+1 complete
    if (k < NT - 2) {
      if constexpr (VS == 6)
        asm volatile("s_waitcnt vmcnt(6) lgkmcnt(0)" ::: "memory");
      else
        asm volatile("s_waitcnt vmcnt(4) lgkmcnt(0)" ::: "memory");
    } else if (k == NT - 2) {
      asm volatile("s_waitcnt vmcnt(0) lgkmcnt(0)" ::: "memory");
    } else {
      asm volatile("s_waitcnt lgkmcnt(0)" ::: "memory");
    }
    __builtin_amdgcn_s_barrier();
    cur = nb;
  }

  // epilogue
  if constexpr (EPI == 0) {
#pragma unroll
    for (int m = 0; m < MR; ++m) {
      const int r0 = tileM + wr * (BM / WM) + m * 16 + lg * 4;
      float psum[4] = {0.f, 0.f, 0.f, 0.f};
#pragma unroll
      for (int n = 0; n < NR; ++n) {
        const int cc = tileN + wc * (BN / WN) + n * 16 + lr;
#pragma unroll
        for (int r = 0; r < 4; ++r) {
          const u16 h = f2bf(__expf(acc[m][n][r] * scale));
          outB[obase + (size_t)(r0 + r) * ldo + cc] = h;
          psum[r] += bf2f(h);
        }
      }
#pragma unroll
      for (int r = 0; r < 4; ++r) {
        float v = psum[r];
        v += __shfl_xor(v, 1, 64); v += __shfl_xor(v, 2, 64);
        v += __shfl_xor(v, 4, 64); v += __shfl_xor(v, 8, 64);
        if (lr == 0) atomicAdd(&bias[(size_t)bz * T + r0 + r], v);
      }
    }
  } else {
#pragma unroll
    for (int m = 0; m < MR; ++m) {
      const int r0 = tileM + wr * (BM / WM) + m * 16 + lg * 4;
#pragma unroll
      for (int n = 0; n < NR; ++n) {
        const int cc = tileN + wc * (BN / WN) + n * 16 + lr;
#pragma unroll
        for (int r = 0; r < 4; ++r) {
          const size_t o = obase + (size_t)(r0 + r) * ldo + cc;
          const float av = acc[m][n][r];
          if constexpr (EPI == 1) {
            outF[o] = resid[o] + av * (1.0f / bias[(size_t)bz * T + r0 + r]);
          } else if constexpr (EPI == 2) {
            const float zz = av + bias[cc];
            const float u = zz * (0.7978845608f + 0.0356774081f * zz * zz);
            const float e = __expf(2.f * u);
            const float th = 1.f - 2.f / (e + 1.f);
            outB[o] = f2bf(0.5f * zz * (1.f + th));
          } else {
            outF[o] = outF[o] + av + bias[cc];
          }
        }
      }
    }
  }
}

extern "C" void kernel_launch(void* const* d_in, const int* in_sizes, int n_in,
                              void* d_out, int out_size, void* d_ws,
                              size_t ws_size, hipStream_t stream) {
  const float* x = (const float*)d_in[0];
  const float* ln1_g = (const float*)d_in[1];
  const float* ln1_b = (const float*)d_in[2];
  const float* ln2_g = (const float*)d_in[3];
  const float* ln2_b = (const float*)d_in[4];
  const float* W1 = (const float*)d_in[5];
  const float* b1 = (const float*)d_in[6];
  const float* W2 = (const float*)d_in[7];
  const float* b2 = (const float*)d_in[8];
  float* out = (float*)d_out;
  char* ws = (char*)d_ws;

  u16* qk = (u16*)(ws + 0);               // 16 MB [B,T,C] bf16 (q == k); later ln2h
  u16* vv = (u16*)(ws + (16LL << 20));    // 16 MB [B,T,C] bf16 (dead after transp)
  u16* vT = (u16*)(ws + (32LL << 20));    // 16 MB [B,C,T] bf16
  u16* S = (u16*)(ws + (48LL << 20));     // 32 MB [B,T,T] bf16 exp-logits
  float* rs = (float*)(ws + (80LL << 20));// 32 KB rowsums (inside h1's later region)
  u16* ln2h = (u16*)(ws + 0);             // reuse qk region
  u16* W1T = (u16*)(ws + (16LL << 20));   // 8 MB [F,C]
  u16* W2T = (u16*)(ws + (24LL << 20));   // 8 MB [C,F]
  u16* h1 = (u16*)(ws + (48LL << 20));    // 64 MB [B*T,F] bf16 (reuse S + rs)

  ln1_rope_k<<<T, 256, 0, stream>>>(x, ln1_g, ln1_b, qk, vv, rs);
  transp_bf16<<<dim3(C / 32, T / 32, Bb), dim3(32, 8), 0, stream>>>(vv, vT, T, C);

  // S = exp(scale * q . q^T) bf16, rowsums -> rs (M=N=T, K=C): 8x8x4 = 256 WGs
  gemm8p<256, 256, 4, 2, 0><<<dim3(T / 256, T / 256, Bb), 512, 0, stream>>>(
      qk, qk, C, C, C, (long long)T * C, (long long)T * C, nullptr, S, T,
      (long long)T * T, rs, nullptr, 1.f / 32.f);

  // out = x + (E . V) / rowsum   (M=T, N=C, K=T): 4x16x4 = 256 WGs
  gemm8p<128, 256, 2, 4, 1><<<dim3(C / 256, T / 128, Bb), 512, 0, stream>>>(
      S, vT, T, T, T, (long long)T * T, (long long)C * T, out,
      nullptr, C, (long long)T * C, rs, x, 1.f);

  ln2_k<<<Bb * T, 256, 0, stream>>>(out, ln2_g, ln2_b, ln2h);
  transp_f32_bf16<<<dim3(F / 32, C / 32, 1), dim3(32, 8), 0, stream>>>(W1, W1T, C, F);
  transp_f32_bf16<<<dim3(C / 32, F / 32, 1), dim3(32, 8), 0, stream>>>(W2, W2T, F, C);

  // h1 = gelu(ln2h . W1 + b1)   (M=B*T, N=F, K=C): 16x32 = 512 WGs
  gemm8p<256, 256, 4, 2, 2><<<dim3(F / 256, (Bb * T) / 256, 1), 512, 0, stream>>>(
      ln2h, W1T, C, C, C, 0, 0, nullptr, h1, F, 0, (float*)b1, nullptr, 1.f);

  // out += h1 . W2 + b2   (M=B*T, N=C, K=F): 4x64 = 256 WGs
  gemm8p<128, 256, 2, 4, 3><<<dim3(C / 256, (Bb * T) / 128, 1), 512, 0, stream>>>(
      h1, W2T, F, F, F, 0, 0, out, nullptr, C, 0, (float*)b2, nullptr, 1.f);
}